// Round 9
// baseline (1225.981 us; speedup 1.0000x reference)
//
#include <hip/hip_runtime.h>
#include <math.h>

#define BB 8
#define NN 1024
#define DD 128
#define HH 2
#define LL 4
#define DFCN 512

typedef __attribute__((ext_vector_type(8))) short bf16x8;
typedef __attribute__((ext_vector_type(8))) _Float16 f16x8;
typedef __attribute__((ext_vector_type(4))) float f32x4;
typedef unsigned long long u64;
typedef unsigned short ushortT;

static __device__ __forceinline__ unsigned short f2bf(float f) {
    unsigned u = __float_as_uint(f);
    u += 0x7FFF + ((u >> 16) & 1);
    return (unsigned short)(u >> 16);
}
static __device__ __forceinline__ float bf2f(unsigned short s) {
    return __uint_as_float(((unsigned)s) << 16);
}
static __device__ __forceinline__ unsigned short f2h(float f) {
    _Float16 h = (_Float16)f; return *(unsigned short*)&h;
}
static __device__ __forceinline__ float h2f(unsigned short u) {
    _Float16 h; *(unsigned short*)&h = u; return (float)h;
}

// ---------------------------------------------------------------------------
// Weight pre-split: W[l][k][n] fp32 -> WT hi/lo [l][n][k] bf16 (32x32 tiles)
// ---------------------------------------------------------------------------
template<int K, int N>
__global__ __launch_bounds__(256) void k_splitWT(const float* __restrict__ W,
                                                 ushortT* __restrict__ Thi,
                                                 ushortT* __restrict__ Tlo) {
    __shared__ float tile[32][33];
    const int l = blockIdx.z;
    const int n0 = blockIdx.x * 32, k0 = blockIdx.y * 32;
    const float* Wl = W + (size_t)l * K * N;
    ushortT* Hl = Thi + (size_t)l * K * N;
    ushortT* Ll = Tlo + (size_t)l * K * N;
    const int t = threadIdx.x;
    const int r = t >> 5, cc = t & 31;
#pragma unroll
    for (int q = 0; q < 4; q++)
        tile[r + q * 8][cc] = Wl[(size_t)(k0 + r + q * 8) * N + n0 + cc];
    __syncthreads();
#pragma unroll
    for (int q = 0; q < 4; q++) {
        const int nl = r + q * 8, kl = cc;
        const float v = tile[kl][nl];
        const ushortT hi = f2bf(v);
        Hl[(size_t)(n0 + nl) * K + k0 + kl] = hi;
        Ll[(size_t)(n0 + nl) * K + k0 + kl] = f2bf(v - bf2f(hi));
    }
}

// ---------------------------------------------------------------------------
// Unified split-bf16 MFMA GEMM (r8 proven).
// ---------------------------------------------------------------------------
template<int K, int N, int TM, bool RELU, int IN_MODE, int OUT_MODE>
__global__ __launch_bounds__(256) void k_mgemm(const ushortT* __restrict__ Ahi,
                                               const ushortT* __restrict__ Alo,
                                               const float* __restrict__ Afp,
                                               const ushortT* __restrict__ BThi,
                                               const ushortT* __restrict__ BTlo,
                                               float* __restrict__ Yf,
                                               ushortT* __restrict__ O1,
                                               ushortT* __restrict__ O2) {
    constexpr int MF = TM / 16;
    constexpr int NW = N / 4;
    constexpr int NF = NW / 16;
    constexpr int SSTG = (TM + N) * 160;
    constexpr int SEPI = TM * (N + 8) * 4;
    constexpr int SMEM = SSTG > SEPI ? SSTG : SEPI;
    __shared__ char smem[SMEM];
    ushortT* sAhi = (ushortT*)smem;
    ushortT* sAlo = sAhi + TM * 40;
    ushortT* sBhi = sAlo + TM * 40;
    ushortT* sBlo = sBhi + (size_t)N * 40;
    const int t = threadIdx.x;
    const int wave = t >> 6, lane = t & 63;
    const int lrow = lane & 15, lg = lane >> 4;
    const int row0 = blockIdx.x * TM;

    f32x4 acc[MF][NF];
#pragma unroll
    for (int m = 0; m < MF; m++)
#pragma unroll
        for (int n = 0; n < NF; n++) {
            acc[m][n][0]=0.f; acc[m][n][1]=0.f; acc[m][n][2]=0.f; acc[m][n][3]=0.f;
        }

    for (int k0 = 0; k0 < K; k0 += 32) {
        __syncthreads();
        if (IN_MODE == 2) {
#pragma unroll
            for (int p = 0; p < TM * 8 / 256; p++) {
                const int idx = t + p * 256;
                const int row = idx >> 3, cu = (idx & 7) * 4;
                const float4 v = *(const float4*)&Afp[(size_t)(row0 + row) * K + k0 + cu];
                ushort4 hi, lo;
                hi.x = f2bf(v.x); lo.x = f2bf(v.x - bf2f(hi.x));
                hi.y = f2bf(v.y); lo.y = f2bf(v.y - bf2f(hi.y));
                hi.z = f2bf(v.z); lo.z = f2bf(v.z - bf2f(hi.z));
                hi.w = f2bf(v.w); lo.w = f2bf(v.w - bf2f(hi.w));
                *(ushort4*)&sAhi[row * 40 + cu] = hi;
                *(ushort4*)&sAlo[row * 40 + cu] = lo;
            }
        } else {
#pragma unroll
            for (int p = 0; p < TM * 8 / 256; p++) {
                const int idx = t + p * 256;
                const bool ishi = idx < TM * 4;
                const int i2 = ishi ? idx : idx - TM * 4;
                const int row = i2 >> 2, cu = (i2 & 3) * 8;
                size_t ga;
                if (IN_MODE == 0) {
                    ga = (size_t)(row0 + row) * K + k0 + cu;
                } else {
                    const int m = row0 + row;
                    const int b = m >> 10, n = m & 1023;
                    const int hh = k0 >> 7, d = (k0 & 127) + cu;
                    ga = (((size_t)(b * 2 + hh) << 10) + n) * DD + d;
                }
                const ushortT* src = ishi ? Ahi : Alo;
                ushortT* dst = ishi ? sAhi : sAlo;
                *(uint4*)&dst[row * 40 + cu] = *(const uint4*)&src[ga];
            }
        }
#pragma unroll
        for (int p = 0; p < N / 32; p++) {
            const int idx = t + p * 256;
            const bool ishi = idx < N * 4;
            const int i2 = ishi ? idx : idx - N * 4;
            const int row = i2 >> 2, cu = (i2 & 3) * 8;
            const ushortT* src = ishi ? BThi : BTlo;
            ushortT* dst = ishi ? sBhi : sBlo;
            *(uint4*)&dst[row * 40 + cu] = *(const uint4*)&src[(size_t)row * K + k0 + cu];
        }
        __syncthreads();
        bf16x8 a0[MF], a1[MF], b0[NF], b1[NF];
#pragma unroll
        for (int m = 0; m < MF; m++) {
            const int off = (m * 16 + lrow) * 40 + lg * 8;
            a0[m] = *(const bf16x8*)&sAhi[off];
            a1[m] = *(const bf16x8*)&sAlo[off];
        }
#pragma unroll
        for (int n = 0; n < NF; n++) {
            const int off = (wave * NW + n * 16 + lrow) * 40 + lg * 8;
            b0[n] = *(const bf16x8*)&sBhi[off];
            b1[n] = *(const bf16x8*)&sBlo[off];
        }
#pragma unroll
        for (int m = 0; m < MF; m++)
#pragma unroll
            for (int n = 0; n < NF; n++) {
                acc[m][n] = __builtin_amdgcn_mfma_f32_16x16x32_bf16(a0[m], b0[n], acc[m][n], 0, 0, 0);
                acc[m][n] = __builtin_amdgcn_mfma_f32_16x16x32_bf16(a0[m], b1[n], acc[m][n], 0, 0, 0);
                acc[m][n] = __builtin_amdgcn_mfma_f32_16x16x32_bf16(a1[m], b0[n], acc[m][n], 0, 0, 0);
            }
    }

    __syncthreads();
    float* tile = (float*)smem;
#pragma unroll
    for (int m = 0; m < MF; m++)
#pragma unroll
        for (int n = 0; n < NF; n++) {
            const int col = wave * NW + n * 16 + lrow;
#pragma unroll
            for (int q = 0; q < 4; q++)
                tile[(m * 16 + lg * 4 + q) * (N + 8) + col] = acc[m][n][q];
        }
    __syncthreads();
#pragma unroll
    for (int p = 0; p < TM * N / 1024; p++) {
        const int idx = t + p * 256;
        const int row = idx / (N / 4), cg = idx % (N / 4);
        float4 v = *(const float4*)&tile[row * (N + 8) + cg * 4];
        if (RELU) {
            v.x = fmaxf(v.x, 0.f); v.y = fmaxf(v.y, 0.f);
            v.z = fmaxf(v.z, 0.f); v.w = fmaxf(v.w, 0.f);
        }
        const int m = row0 + row;
        if (OUT_MODE == 0) {
            *(float4*)&Yf[(size_t)m * N + cg * 4] = v;
        } else {
            ushort4 hi, lo;
            hi.x = f2bf(v.x); lo.x = f2bf(v.x - bf2f(hi.x));
            hi.y = f2bf(v.y); lo.y = f2bf(v.y - bf2f(hi.y));
            hi.z = f2bf(v.z); lo.z = f2bf(v.z - bf2f(hi.z));
            hi.w = f2bf(v.w); lo.w = f2bf(v.w - bf2f(hi.w));
            if (OUT_MODE == 1) {
                const int b = m >> 10, n = m & 1023;
                const int col = cg * 4;
                const int hh = col >> 7, d = col & 127;
                const size_t addr = (((size_t)(b * 2 + hh) << 10) + n) * DD + d;
                *(float4*)&Yf[addr] = v;
                *(ushort4*)&O1[addr] = hi;
                *(ushort4*)&O2[addr] = lo;
            } else {
                const size_t addr = (size_t)m * N + cg * 4;
                if (OUT_MODE == 3) *(float4*)&Yf[addr] = v;
                *(ushort4*)&O1[addr] = hi;
                *(ushort4*)&O2[addr] = lo;
            }
        }
    }
}

// ---------------------------------------------------------------------------
// e = sym MFMA (r7 proven: f16 e, upper-tri, coalesced dual write, XCD swz)
// ---------------------------------------------------------------------------
__global__ __launch_bounds__(256) void k_esym_mfma(const ushortT* __restrict__ wHi,
                                                   const ushortT* __restrict__ wLo,
                                                   const ushortT* __restrict__ hHi,
                                                   const ushortT* __restrict__ hLo,
                                                   ushortT* __restrict__ e) {
    __shared__ ushortT smem[20480];
    ushortT* sWjHi = smem;
    ushortT* sWjLo = smem + 2560;
    ushortT* sHjHi = smem + 5120;
    ushortT* sHjLo = smem + 7680;
    ushortT* sWkHi = smem + 10240;
    ushortT* sWkLo = smem + 12800;
    ushortT* sHkHi = smem + 15360;
    ushortT* sHkLo = smem + 17920;

    const int wgid = blockIdx.x;
    const int flat = (wgid & 7) * 272 + (wgid >> 3);
    const int bh = flat / 136;
    int idx = flat % 136, tj = 0;
    while (idx >= 16 - tj) { idx -= 16 - tj; tj++; }
    const int tk = tj + idx;
    const int j0 = tj * 64, k0 = tk * 64;
    const int t = threadIdx.x;
    const int wave = t >> 6, lane = t & 63;
    const int wr = wave >> 1, wc = wave & 1;
    const int lrow = lane & 15, lg = lane >> 4;

    f32x4 acc[2][2];
#pragma unroll
    for (int m = 0; m < 2; m++)
#pragma unroll
        for (int n = 0; n < 2; n++) {
            acc[m][n][0] = 0.f; acc[m][n][1] = 0.f;
            acc[m][n][2] = 0.f; acc[m][n][3] = 0.f;
        }

    const size_t bhbase = (size_t)bh * NN * DD;

    for (int d0 = 0; d0 < DD; d0 += 32) {
        __syncthreads();
        {
            const int row = t >> 2, cu = (t & 3) * 8;
#define STAGE1(SRC, DST, BASE)                                                    \
            *(uint4*)&DST[row * 40 + cu] =                                        \
                *(const uint4*)&SRC[bhbase + (size_t)(BASE + row) * DD + d0 + cu];
            STAGE1(wHi, sWjHi, j0) STAGE1(wLo, sWjLo, j0)
            STAGE1(hHi, sHjHi, j0) STAGE1(hLo, sHjLo, j0)
            STAGE1(wHi, sWkHi, k0) STAGE1(wLo, sWkLo, k0)
            STAGE1(hHi, sHkHi, k0) STAGE1(hLo, sHkLo, k0)
#undef STAGE1
        }
        __syncthreads();

        bf16x8 a0[2], a1[2], b0[2], b1[2];
#pragma unroll
        for (int m = 0; m < 2; m++) {
            const int off = (wr * 32 + m * 16 + lrow) * 40 + lg * 8;
            a0[m] = *(const bf16x8*)&sWjHi[off];
            a1[m] = *(const bf16x8*)&sWjLo[off];
        }
#pragma unroll
        for (int n = 0; n < 2; n++) {
            const int off = (wc * 32 + n * 16 + lrow) * 40 + lg * 8;
            b0[n] = *(const bf16x8*)&sHkHi[off];
            b1[n] = *(const bf16x8*)&sHkLo[off];
        }
#pragma unroll
        for (int m = 0; m < 2; m++)
#pragma unroll
            for (int n = 0; n < 2; n++) {
                acc[m][n] = __builtin_amdgcn_mfma_f32_16x16x32_bf16(a0[m], b0[n], acc[m][n], 0, 0, 0);
                acc[m][n] = __builtin_amdgcn_mfma_f32_16x16x32_bf16(a0[m], b1[n], acc[m][n], 0, 0, 0);
                acc[m][n] = __builtin_amdgcn_mfma_f32_16x16x32_bf16(a1[m], b0[n], acc[m][n], 0, 0, 0);
            }
#pragma unroll
        for (int m = 0; m < 2; m++) {
            const int off = (wr * 32 + m * 16 + lrow) * 40 + lg * 8;
            a0[m] = *(const bf16x8*)&sHjHi[off];
            a1[m] = *(const bf16x8*)&sHjLo[off];
        }
#pragma unroll
        for (int n = 0; n < 2; n++) {
            const int off = (wc * 32 + n * 16 + lrow) * 40 + lg * 8;
            b0[n] = *(const bf16x8*)&sWkHi[off];
            b1[n] = *(const bf16x8*)&sWkLo[off];
        }
#pragma unroll
        for (int m = 0; m < 2; m++)
#pragma unroll
            for (int n = 0; n < 2; n++) {
                acc[m][n] = __builtin_amdgcn_mfma_f32_16x16x32_bf16(a0[m], b0[n], acc[m][n], 0, 0, 0);
                acc[m][n] = __builtin_amdgcn_mfma_f32_16x16x32_bf16(a0[m], b1[n], acc[m][n], 0, 0, 0);
                acc[m][n] = __builtin_amdgcn_mfma_f32_16x16x32_bf16(a1[m], b0[n], acc[m][n], 0, 0, 0);
            }
    }

    __syncthreads();
    ushortT* tileN = smem;
    ushortT* tileT = smem + 4608;
#pragma unroll
    for (int m = 0; m < 2; m++)
#pragma unroll
        for (int n = 0; n < 2; n++) {
            const int jlb = wr * 32 + m * 16 + lg * 4;
            const int kl  = wc * 32 + n * 16 + lrow;
            ushort4 tv;
            tv.x = f2h(acc[m][n][0]); tv.y = f2h(acc[m][n][1]);
            tv.z = f2h(acc[m][n][2]); tv.w = f2h(acc[m][n][3]);
            tileN[(jlb + 0) * 72 + kl] = tv.x;
            tileN[(jlb + 1) * 72 + kl] = tv.y;
            tileN[(jlb + 2) * 72 + kl] = tv.z;
            tileN[(jlb + 3) * 72 + kl] = tv.w;
            *(ushort4*)&tileT[kl * 72 + jlb] = tv;
        }
    __syncthreads();
#pragma unroll
    for (int it = 0; it < 4; it++) {
        const int i2 = t + it * 256;
        const int row = i2 >> 4, ch = (i2 & 15) * 4;
        *(uint2*)&e[((size_t)bh * NN + j0 + row) * NN + k0 + ch] =
            *(const uint2*)&tileN[row * 72 + ch];
        if (tj != tk)
            *(uint2*)&e[((size_t)bh * NN + k0 + row) * NN + j0 + ch] =
                *(const uint2*)&tileT[row * 72 + ch];
    }
}

// ---------------------------------------------------------------------------
__global__ __launch_bounds__(256) void k_buildT(const float* __restrict__ adj,
                                                u64* __restrict__ bits) {
    const int gid = blockIdx.x * 256 + threadIdx.x;
    const int k  = gid & 1023;
    const int tw = (gid >> 10) & 15;
    const int b  = gid >> 14;
    const float* ac = adj + ((size_t)b << 20) + k;
    u64 w = 0;
#pragma unroll 8
    for (int jj = 0; jj < 64; jj++) {
        if (ac[(size_t)(tw * 64 + jj) << 10] != 0.f) w |= 1ull << jj;
    }
    bits[((size_t)((b << 10) | k)) * 16 + tw] = w;
}

__global__ __launch_bounds__(256) void k_cnt(const u64* __restrict__ bits,
                                             int* __restrict__ ccnt) {
    const int gid = blockIdx.x * 256 + threadIdx.x;
    const u64* wb = bits + (size_t)gid * 16;
    int c = 0;
#pragma unroll
    for (int tw = 0; tw < 16; tw++) c += __popcll(wb[tw]);
    ccnt[gid] = c;
}

// ---------------------------------------------------------------------------
__global__ __launch_bounds__(256) void k_smA(const ushortT* __restrict__ e,
                                             const u64* __restrict__ bits,
                                             float* __restrict__ pm,
                                             float* __restrict__ ps) {
    const int gid = blockIdx.x * 256 + threadIdx.x;
    const int kg = gid & 255;
    const int jc = (gid >> 8) & 63;
    const int bh = gid >> 14;
    const int b  = bh >> 1;
    const int k4 = kg * 4;
    const int tw = jc >> 2;
    const int bo = (jc & 3) * 16;
    u64 w[4];
#pragma unroll
    for (int i = 0; i < 4; i++)
        w[i] = bits[((size_t)((b << 10) | (k4 + i))) * 16 + tw];
    const ushortT* ec = e + ((size_t)bh << 20) + (size_t)(jc * 16) * NN + k4;
    float m[4] = {0.f, 0.f, 0.f, 0.f};
    float s[4] = {0.f, 0.f, 0.f, 0.f};
#pragma unroll
    for (int r = 0; r < 16; r++) {
        const ushort4 ev = *(const ushort4*)&ec[(size_t)r * NN];
        const float evs[4] = {h2f(ev.x), h2f(ev.y), h2f(ev.z), h2f(ev.w)};
#pragma unroll
        for (int i = 0; i < 4; i++) {
            const bool on = (w[i] >> (bo + r)) & 1;
            const float v = on ? evs[i] : 0.f;
            const float mn = fmaxf(m[i], v);
            s[i] = s[i] * __expf(m[i] - mn) + (on ? __expf(v - mn) : 0.f);
            m[i] = mn;
        }
    }
    const size_t o = (((size_t)bh * 64 + jc) << 10) + k4;
    *(float4*)&pm[o] = make_float4(m[0], m[1], m[2], m[3]);
    *(float4*)&ps[o] = make_float4(s[0], s[1], s[2], s[3]);
}

__global__ __launch_bounds__(256) void k_smB(const float* __restrict__ pm,
                                             const float* __restrict__ ps,
                                             const int* __restrict__ ccnt,
                                             float* __restrict__ smax,
                                             float* __restrict__ sdinv) {
    __shared__ float lm[4][64], ls[4][64];
    const int t = threadIdx.x, q = t >> 6, lane = t & 63;
    const int colg = blockIdx.x * 64 + lane;
    const int bh = colg >> 10, k = colg & 1023;
    const int b  = bh >> 1;
    float M = 0.f, S = 0.f;
#pragma unroll 4
    for (int i = 0; i < 16; i++) {
        const int jc = q * 16 + i;
        const size_t o = (((size_t)bh * 64 + jc) << 10) + k;
        const float pmv = pm[o], psv = ps[o];
        const float mn = fmaxf(M, pmv);
        S = S * __expf(M - mn) + psv * __expf(pmv - mn);
        M = mn;
    }
    lm[q][lane] = M; ls[q][lane] = S;
    __syncthreads();
    if (q == 0) {
#pragma unroll
        for (int qq = 1; qq < 4; qq++) {
            const float pmv = lm[qq][lane], psv = ls[qq][lane];
            const float mn = fmaxf(M, pmv);
            S = S * __expf(M - mn) + psv * __expf(pmv - mn);
            M = mn;
        }
        S += (float)(NN - ccnt[(b << 10) + k]) * __expf(-M);
        smax[colg] = M;
        sdinv[colg] = 1.f / S;
    }
}

__global__ __launch_bounds__(256) void k_smC(const ushortT* __restrict__ e,
                                             const u64* __restrict__ bits,
                                             const float* __restrict__ smax,
                                             const float* __restrict__ sdinv,
                                             ushortT* __restrict__ att) {
    const int gid = blockIdx.x * 256 + threadIdx.x;
    const int kg = gid & 255;
    const int jc = (gid >> 8) & 63;
    const int bh = gid >> 14;
    const int b  = bh >> 1;
    const int k4 = kg * 4;
    const int tw = jc >> 2;
    const int bo = (jc & 3) * 16;
    u64 w[4];
#pragma unroll
    for (int i = 0; i < 4; i++)
        w[i] = bits[((size_t)((b << 10) | (k4 + i))) * 16 + tw];
    const float4 m4 = *(const float4*)&smax[(bh << 10) + k4];
    const float4 d4 = *(const float4*)&sdinv[(bh << 10) + k4];
    const float ms[4] = {m4.x, m4.y, m4.z, m4.w};
    const float ds[4] = {d4.x, d4.y, d4.z, d4.w};
    const ushortT* ec = e + ((size_t)bh << 20) + (size_t)(jc * 16) * NN + k4;
    ushortT* ac = att + ((size_t)bh << 20) + (size_t)(jc * 16) * NN + k4;
#pragma unroll
    for (int r = 0; r < 16; r++) {
        const ushort4 ev = *(const ushort4*)&ec[(size_t)r * NN];
        const float evs[4] = {h2f(ev.x), h2f(ev.y), h2f(ev.z), h2f(ev.w)};
        ushort4 o;
        ushortT os[4];
#pragma unroll
        for (int i = 0; i < 4; i++) {
            const bool on = (w[i] >> (bo + r)) & 1;
            os[i] = f2h(on ? __expf(evs[i] - ms[i]) * ds[i] : 0.f);
        }
        o.x = os[0]; o.y = os[1]; o.z = os[2]; o.w = os[3];
        *(ushort4*)&ac[(size_t)r * NN] = o;
    }
}

// ---------------------------------------------------------------------------
__global__ __launch_bounds__(256) void k_trT(const float* __restrict__ h,
                                             ushortT* __restrict__ hT) {
    __shared__ float tile[64][65];
    const int bh = blockIdx.z;
    const int n0 = blockIdx.x * 64, d0 = blockIdx.y * 64;
    const int t = threadIdx.x;
#pragma unroll
    for (int q = 0; q < 16; q++) {
        const int idx = t + q * 256;
        const int row = idx >> 6, col = idx & 63;
        tile[row][col] = h[(size_t)bh * 131072 + (size_t)(n0 + row) * DD + d0 + col];
    }
    __syncthreads();
#pragma unroll
    for (int q = 0; q < 16; q++) {
        const int idx = t + q * 256;
        const int row = idx >> 6, col = idx & 63;
        hT[(size_t)bh * 131072 + (size_t)(d0 + row) * NN + n0 + col] = f2h(tile[col][row]);
    }
}

// Final mix + relu + bf16-split: z = beta*h + (1-beta)*az -> zHi/zLo [bh][n][d]
__global__ __launch_bounds__(256) void k_finmix(const ushortT* __restrict__ azT,
                                                const ushortT* __restrict__ hT,
                                                const float* __restrict__ beta,
                                                ushortT* __restrict__ zHi,
                                                ushortT* __restrict__ zLo) {
    __shared__ float tile[64][65];
    const int bh = blockIdx.z;
    const int n0 = blockIdx.x * 64, d0 = blockIdx.y * 64;
    const int t = threadIdx.x;
    const float* betab = beta + ((size_t)bh << 10);
#pragma unroll
    for (int q = 0; q < 16; q++) {
        const int idx = t + q * 256;
        const int row = idx >> 6, col = idx & 63;     // row = d-local, col = n-local
        const size_t ga = (size_t)bh * 131072 + (size_t)(d0 + row) * NN + n0 + col;
        const float be = betab[n0 + col];
        tile[row][col] = be * h2f(hT[ga]) + (1.f - be) * h2f(azT[ga]);
    }
    __syncthreads();
#pragma unroll
    for (int q = 0; q < 16; q++) {
        const int idx = t + q * 256;
        const int row = idx >> 6, col = idx & 63;     // row = n-local, col = d-local
        const float v = fmaxf(tile[col][row], 0.f);
        const ushortT hi = f2bf(v);
        const size_t addr = (size_t)bh * 131072 + (size_t)(n0 + row) * DD + d0 + col;
        zHi[addr] = hi;
        zLo[addr] = f2bf(v - bf2f(hi));
    }
}

// ---------------------------------------------------------------------------
// Dense f16 MFMA hop, 8 waves, j-chunk 128, XCD swizzle.
// MODE 0: zin = hT; writes raw az; computes beta in epilogue (az0 + h).
// MODE 1: zin = beta*hT + (1-beta)*azprev, mixed during staging; writes raw az.
// ---------------------------------------------------------------------------
template<int MODE>
__global__ __launch_bounds__(512) void k_hop(const ushortT* __restrict__ att,
                                             const ushortT* __restrict__ azprev,
                                             const ushortT* __restrict__ hT,
                                             float* __restrict__ beta,
                                             const float* __restrict__ Wbw,
                                             const float* __restrict__ Wbb,
                                             ushortT* __restrict__ azout) {
    __shared__ ushortT smem[64 * 136 + 128 * 136];
    ushortT* sA = smem;                         // [64][136]
    ushortT* sB = smem + 64 * 136;              // [128][136]
    const int bid = blockIdx.x;                 // 256 = 8 XCD x 32
    const int flat = (bid & 7) * 32 + (bid >> 3);
    const int bh = flat >> 4;
    const int i0 = (flat & 15) * 64;
    const int t = threadIdx.x, wave = t >> 6, lane = t & 63;
    const int wr = wave >> 2, wc = wave & 3;
    const int lrow = lane & 15, lg = lane >> 4;
    const ushortT* attb = att + ((size_t)bh << 20);
    const ushortT* hTb  = hT + (size_t)bh * 131072;
    const ushortT* azb  = (MODE == 1) ? azprev + (size_t)bh * 131072 : nullptr;
    const float* betab  = beta + ((size_t)bh << 10);

    f32x4 acc[2][2];
#pragma unroll
    for (int m = 0; m < 2; m++)
#pragma unroll
        for (int n = 0; n < 2; n++) {
            acc[m][n][0]=0.f; acc[m][n][1]=0.f; acc[m][n][2]=0.f; acc[m][n][3]=0.f;
        }

    for (int j0 = 0; j0 < NN; j0 += 128) {
        __syncthreads();
#pragma unroll
        for (int q = 0; q < 2; q++) {           // sA: 64x128 = 1024 uint4
            const int u = t + q * 512;
            const int row = u >> 4, c8 = (u & 15) * 8;
            *(uint4*)&sA[row * 136 + c8] =
                *(const uint4*)&attb[(size_t)(i0 + row) * NN + j0 + c8];
        }
#pragma unroll
        for (int q = 0; q < 4; q++) {           // sB: 128x128 = 2048 uint4
            const int u = t + q * 512;
            const int row = u >> 4, c8 = (u & 15) * 8;
            if (MODE == 0) {
                *(uint4*)&sB[row * 136 + c8] =
                    *(const uint4*)&hTb[(size_t)row * NN + j0 + c8];
            } else {
                ushortT hu[8], au[8], ou[8];
                *(uint4*)hu = *(const uint4*)&hTb[(size_t)row * NN + j0 + c8];
                *(uint4*)au = *(const uint4*)&azb[(size_t)row * NN + j0 + c8];
                const float4 b0 = *(const float4*)&betab[j0 + c8];
                const float4 b1 = *(const float4*)&betab[j0 + c8 + 4];
                const float be[8] = {b0.x, b0.y, b0.z, b0.w, b1.x, b1.y, b1.z, b1.w};
#pragma unroll
                for (int i = 0; i < 8; i++)
                    ou[i] = f2h(be[i] * h2f(hu[i]) + (1.f - be[i]) * h2f(au[i]));
                *(uint4*)&sB[row * 136 + c8] = *(uint4*)ou;
            }
        }
        __syncthreads();
#pragma unroll
        for (int ks = 0; ks < 4; ks++) {
            f16x8 a[2], b[2];
#pragma unroll
            for (int m = 0; m < 2; m++)
                a[m] = *(const f16x8*)&sA[(wr * 32 + m * 16 + lrow) * 136 + ks * 32 + lg * 8];
#pragma unroll
            for (int n = 0; n < 2; n++)
                b[n] = *(const f16x8*)&sB[(wc * 32 + n * 16 + lrow) * 136 + ks * 32 + lg * 8];
#pragma unroll
            for (int m = 0; m < 2; m++)
#pragma unroll
                for (int n = 0; n < 2; n++)
                    acc[m][n] = __builtin_amdgcn_mfma_f32_16x16x32_f16(a[m], b[n], acc[m][n], 0, 0, 0);
        }
    }

    // epilogue: write raw az (relu), transposed [d][n]
    ushortT* zo = azout + (size_t)bh * 131072;
    ushort4 ofrag[2][2];
#pragma unroll
    for (int m = 0; m < 2; m++)
#pragma unroll
        for (int n = 0; n < 2; n++) {
            const int d = wc * 32 + n * 16 + lrow;
            const int i = i0 + wr * 32 + m * 16 + lg * 4;
            ushort4 o;
            o.x = f2h(fmaxf(acc[m][n][0], 0.f));
            o.y = f2h(fmaxf(acc[m][n][1], 0.f));
            o.z = f2h(fmaxf(acc[m][n][2], 0.f));
            o.w = f2h(fmaxf(acc[m][n][3], 0.f));
            ofrag[m][n] = o;
            *(ushort4*)&zo[(size_t)d * NN + i] = o;
        }

    if (MODE == 0) {
        // ---- fused beta: beta[n] = sigmoid(h[n].Wbw[0:128] + az[n].Wbw[128:256] + bb)
        __syncthreads();                        // staging LDS dead; reuse
        ushortT* azl = smem;                    // [128][72]
        ushortT* hl  = smem + 128 * 72;         // [128][72]
#pragma unroll
        for (int m = 0; m < 2; m++)
#pragma unroll
            for (int n = 0; n < 2; n++) {
                const int d = wc * 32 + n * 16 + lrow;
                const int il = wr * 32 + m * 16 + lg * 4;
                const ushort4 o = ofrag[m][n];
                azl[d * 72 + il + 0] = o.x;
                azl[d * 72 + il + 1] = o.y;
                azl[d * 72 + il + 2] = o.z;
                azl[d * 72 + il + 3] = o.w;
            }
#pragma unroll
        for (int q = 0; q < 2; q++) {           // hl: 128 rows x 64 cols
            const int u = t + q * 512;
            const int row = u >> 3, c8 = (u & 7) * 8;
            *(uint4*)&hl[row * 72 + c8] =
                *(const uint4*)&hTb[(size_t)row * NN + i0 + c8];
        }
        __syncthreads();
        const int i = t >> 3, c = t & 7;        // i: 0..63, c: d-chunk 0..7
        float p = 0.f;
#pragma unroll
        for (int dd = 0; dd < 16; dd++) {
            const int d = c * 16 + dd;
            p += h2f(hl[d * 72 + i]) * Wbw[d] + h2f(azl[d * 72 + i]) * Wbw[DD + d];
        }
        p += __shfl_down(p, 4, 8);
        p += __shfl_down(p, 2, 8);
        p += __shfl_down(p, 1, 8);
        if (c == 0)
            beta[(bh << 10) + i0 + i] = 1.f / (1.f + expf(-(p + Wbb[0])));
    }
}

// c = c2 - c1 fp32 + bf16 hi/lo split
__global__ __launch_bounds__(256) void k_sub(const float* __restrict__ c2,
                                             const float* __restrict__ c1,
                                             float* __restrict__ c,
                                             ushortT* __restrict__ cHi,
                                             ushortT* __restrict__ cLo) {
    const int g = blockIdx.x * 256 + threadIdx.x;
    const float4 a = ((const float4*)c2)[g];
    const float4 b = ((const float4*)c1)[g];
    const float4 v = make_float4(a.x - b.x, a.y - b.y, a.z - b.z, a.w - b.w);
    ((float4*)c)[g] = v;
    ushort4 hi, lo;
    hi.x = f2bf(v.x); lo.x = f2bf(v.x - bf2f(hi.x));
    hi.y = f2bf(v.y); lo.y = f2bf(v.y - bf2f(hi.y));
    hi.z = f2bf(v.z); lo.z = f2bf(v.z - bf2f(hi.z));
    hi.w = f2bf(v.w); lo.w = f2bf(v.w - bf2f(hi.w));
    ((ushort4*)cHi)[g] = hi;
    ((ushort4*)cLo)[g] = lo;
}

__global__ __launch_bounds__(128) void k_poolA(const float* __restrict__ c,
                                               const float* __restrict__ valid,
                                               float* __restrict__ pp,
                                               float* __restrict__ pv) {
    const int bc = blockIdx.x;
    const int b = bc >> 4, ch = bc & 15;
    const int d = threadIdx.x;
    const float* cb = c + ((size_t)b << 17) + (size_t)(ch * 64) * DD;
    const float* vb = valid + (b << 10) + ch * 64;
    float s = 0.f, sv = 0.f;
#pragma unroll 8
    for (int i = 0; i < 64; i++) { const float v = vb[i]; s += cb[(size_t)i * DD + d] * v; sv += v; }
    pp[bc * 128 + d] = s;
    if (d == 0) pv[bc] = sv;
}

__global__ __launch_bounds__(256) void k_poolB(const float* __restrict__ pp,
                                               const float* __restrict__ pv,
                                               float* __restrict__ pooled) {
    const int gid = blockIdx.x * 256 + threadIdx.x;
    const int b = gid >> 7, d = gid & 127;
    float s = 0.f, sv = 0.f;
#pragma unroll
    for (int ch = 0; ch < 16; ch++) {
        s  += pp[(b * 16 + ch) * 128 + d];
        sv += pv[b * 16 + ch];
    }
    pooled[b * 128 + d] = s / sv;
}

template<int K, int NOUT, bool RELU>
__global__ void k_fc(const float* __restrict__ X, const float* __restrict__ W,
                     const float* __restrict__ bias, float* __restrict__ Y) {
    const int gid = blockIdx.x * blockDim.x + threadIdx.x;
    if (gid >= BB * NOUT) return;
    const int b = gid / NOUT, o = gid % NOUT;
    float s = bias[o];
    for (int i = 0; i < K; i++) s += X[(size_t)b * K + i] * W[(size_t)i * NOUT + o];
    Y[gid] = RELU ? fmaxf(s, 0.f) : s;
}

__global__ void k_fc2(const float* __restrict__ X, const float* __restrict__ W,
                      const float* __restrict__ bias, float* __restrict__ out) {
    const int b = threadIdx.x >> 6, lane = threadIdx.x & 63;
    float s = 0.f;
    for (int i = lane; i < DFCN; i += 64) s += X[(size_t)b * DFCN + i] * W[i];
#pragma unroll
    for (int off = 32; off > 0; off >>= 1) s += __shfl_down(s, off);
    if (lane == 0) out[b] = 1.f / (1.f + expf(-(s + bias[0])));
}

// ---------------------------------------------------------------------------
extern "C" void kernel_launch(void* const* d_in, const int* in_sizes, int n_in,
                              void* d_out, int out_size, void* d_ws, size_t ws_size,
                              hipStream_t stream) {
    const float* x        = (const float*)d_in[0];
    const float* adj1     = (const float*)d_in[1];
    const float* adj2     = (const float*)d_in[2];
    const float* valid    = (const float*)d_in[3];
    const float* embede_w = (const float*)d_in[4];
    const float* Wh       = (const float*)d_in[5];
    const float* We       = (const float*)d_in[6];
    const float* Wbw      = (const float*)d_in[7];
    const float* Wbb      = (const float*)d_in[8];
    const float* Wo       = (const float*)d_in[9];
    const float* fc0_w    = (const float*)d_in[10];
    const float* fc0_b    = (const float*)d_in[11];
    const float* fc1_w    = (const float*)d_in[12];
    const float* fc1_b    = (const float*)d_in[13];
    const float* fc2_w    = (const float*)d_in[14];
    const float* fc2_b    = (const float*)d_in[15];

    // ---- workspace carve ----
    float* ws = (float*)d_ws;
    float* c      = ws;                          // 1,048,576 f
    float* h      = c      + (size_t)1048576;    // 2,097,152 f
    float* c1     = h      + (size_t)2097152;    // 1,048,576 f
    float* c2     = c1     + (size_t)1048576;    // 1,048,576 f
    float* beta   = c2     + (size_t)1048576;    // 16,384 f
    float* pm     = beta   + (size_t)16384;      // 1,048,576 f
    float* ps     = pm     + (size_t)1048576;    // 1,048,576 f
    float* smax   = ps     + (size_t)1048576;    // 16,384 f
    float* sdinv  = smax   + (size_t)16384;      // 16,384 f
    float* pp     = sdinv  + (size_t)16384;      // 16,384 f
    float* pv     = pp     + (size_t)16384;      // 128 f
    float* pooled = pv     + (size_t)128;        // 1,024 f
    float* f0     = pooled + (size_t)1024;       // 4,096 f
    float* f1     = f0     + (size_t)4096;       // 4,096 f
    ushortT* hHi  = (ushortT*)(f1 + 4096);       // 2,097,152 us each
    ushortT* hLo  = hHi + (size_t)2097152;
    ushortT* wHi  = hLo + (size_t)2097152;
    ushortT* wLo  = wHi + (size_t)2097152;
    ushortT* hT   = wLo + (size_t)2097152;
    ushortT* zTa  = hT  + (size_t)2097152;
    ushortT* zTb  = zTa + (size_t)2097152;
    ushortT* cHi  = zTb + (size_t)2097152;       // 1,048,576 us each
    ushortT* cLo  = cHi + (size_t)1048576;
    ushortT* zHi  = cLo + (size_t)1048576;       // 2,097,152 us each
    ushortT* zLo  = zHi + (size_t)2097152;
    ushortT* att  = zLo + (size_t)2097152;       // 16,777,216 us
    ushortT* e    = att + (size_t)16777216;      // 16,777,216 us
    ushortT* WhTh = e   + (size_t)16777216;      // 131,072 us each
    ushortT* WhTl = WhTh + (size_t)131072;
    ushortT* WeTh = WhTl + (size_t)131072;       // 65,536 each
    ushortT* WeTl = WeTh + (size_t)65536;
    ushortT* WoTh = WeTl + (size_t)65536;        // 131,072 each
    ushortT* WoTl = WoTh + (size_t)131072;
    ushortT* EmTh = WoTl + (size_t)131072;       // 16,384 each
    ushortT* EmTl = EmTh + (size_t)16384;
    u64* bits1    = (u64*)(EmTl + (size_t)16384);
    u64* bits2    = bits1 + (size_t)131072;
    int* ccnt1    = (int*)(bits2 + (size_t)131072);
    int* ccnt2    = ccnt1 + 8192;

    // ---- one-time per launch: masks + weight splits ----
    k_buildT<<<512, 256, 0, stream>>>(adj1, bits1);
    k_buildT<<<512, 256, 0, stream>>>(adj2, bits2);
    k_cnt<<<32, 256, 0, stream>>>(bits1, ccnt1);
    k_cnt<<<32, 256, 0, stream>>>(bits2, ccnt2);
    k_splitWT<128,256><<<dim3(8,4,4), 256, 0, stream>>>(Wh, WhTh, WhTl);
    k_splitWT<128,128><<<dim3(4,4,4), 256, 0, stream>>>(We, WeTh, WeTl);
    k_splitWT<256,128><<<dim3(4,8,4), 256, 0, stream>>>(Wo, WoTh, WoTl);
    k_splitWT<128,128><<<dim3(4,4,1), 256, 0, stream>>>(embede_w, EmTh, EmTl);

    // c = x @ embede_w
    k_mgemm<128,128,32,false,2,3><<<256, 256, 0, stream>>>(
        nullptr, nullptr, x, EmTh, EmTl, c, cHi, cLo);

    for (int k = 0; k < LL; k++) {
        const int nhop = k + 1;
        const float* Wbw_k = Wbw + (size_t)k * 256;
        const float* Wbb_k = Wbb + k;
        // h = relu(c @ Wh[k]) -> scatter [bh][n][d] fp32 + splits
        k_mgemm<128,256,32,true,0,1><<<256, 256, 0, stream>>>(
            cHi, cLo, nullptr, WhTh + (size_t)k*32768, WhTl + (size_t)k*32768, h, hHi, hLo);
        // hW = h @ We[k] -> splits row-major
        k_mgemm<128,128,64,false,0,2><<<256, 256, 0, stream>>>(
            hHi, hLo, nullptr, WeTh + (size_t)k*16384, WeTl + (size_t)k*16384, nullptr, wHi, wLo);
        k_trT<<<dim3(16,2,16), 256, 0, stream>>>(h, hT);
        k_esym_mfma<<<2176, 256, 0, stream>>>(wHi, wLo, hHi, hLo, e);

        for (int br = 0; br < 2; br++) {
            const u64* bits = (br == 0) ? bits1 : bits2;
            const int* ccnt = (br == 0) ? ccnt1 : ccnt2;
            float*     cb   = (br == 0) ? c1    : c2;

            k_smA<<<1024, 256, 0, stream>>>(e, bits, pm, ps);
            k_smB<<<256, 256, 0, stream>>>(pm, ps, ccnt, smax, sdinv);
            k_smC<<<1024, 256, 0, stream>>>(e, bits, smax, sdinv, att);

            // hop0: az0 = relu(att@h); beta computed in-kernel
            k_hop<0><<<256, 512, 0, stream>>>(att, nullptr, hT, beta, Wbw_k, Wbb_k, zTb);
            // hops 1..nhop-1: stage-mix z_{t-1}, write raw az_t
            ushortT* zA = zTb; ushortT* zB = zTa;
            for (int tpp = 1; tpp < nhop; tpp++) {
                k_hop<1><<<256, 512, 0, stream>>>(att, zA, hT, beta, nullptr, nullptr, zB);
                ushortT* tmp = zA; zA = zB; zB = tmp;
            }
            // final: z = beta*h + (1-beta)*az_last, relu + split -> [n][d]
            k_finmix<<<dim3(16,2,16), 256, 0, stream>>>(zA, hT, beta, zHi, zLo);
            k_mgemm<256,128,32,false,1,0><<<256, 256, 0, stream>>>(
                zHi, zLo, nullptr, WoTh + (size_t)k*32768, WoTl + (size_t)k*32768, cb, nullptr, nullptr);
        }
        k_sub<<<1024, 256, 0, stream>>>(c2, c1, c, cHi, cLo);
    }

    k_poolA<<<128, 128, 0, stream>>>(c, valid, pp, pv);
    k_poolB<<<4, 256, 0, stream>>>(pp, pv, pooled);
    k_fc<128, DFCN, true><<<16, 256, 0, stream>>>(pooled, fc0_w, fc0_b, f0);
    k_fc<DFCN, DFCN, true><<<16, 256, 0, stream>>>(f0, fc1_w, fc1_b, f1);
    k_fc2<<<1, 512, 0, stream>>>(f1, fc2_w, fc2_b, (float*)d_out);
}

// Round 10
// 1099.964 us; speedup vs baseline: 1.1146x; 1.1146x over previous
//
#include <hip/hip_runtime.h>
#include <math.h>

#define BB 8
#define NN 1024
#define DD 128
#define HH 2
#define LL 4
#define DFCN 512

typedef __attribute__((ext_vector_type(8))) short bf16x8;
typedef __attribute__((ext_vector_type(8))) _Float16 f16x8;
typedef __attribute__((ext_vector_type(4))) float f32x4;
typedef unsigned long long u64;
typedef unsigned short ushortT;

static __device__ __forceinline__ unsigned short f2bf(float f) {
    unsigned u = __float_as_uint(f);
    u += 0x7FFF + ((u >> 16) & 1);
    return (unsigned short)(u >> 16);
}
static __device__ __forceinline__ float bf2f(unsigned short s) {
    return __uint_as_float(((unsigned)s) << 16);
}
static __device__ __forceinline__ unsigned short f2h(float f) {
    _Float16 h = (_Float16)f; return *(unsigned short*)&h;
}
static __device__ __forceinline__ float h2f(unsigned short u) {
    _Float16 h; *(unsigned short*)&h = u; return (float)h;
}

// ---------------------------------------------------------------------------
// Weight pre-split: W[l][k][n] fp32 -> WT hi/lo [l][n][k] bf16 (32x32 tiles)
// ---------------------------------------------------------------------------
template<int K, int N>
__global__ __launch_bounds__(256) void k_splitWT(const float* __restrict__ W,
                                                 ushortT* __restrict__ Thi,
                                                 ushortT* __restrict__ Tlo) {
    __shared__ float tile[32][33];
    const int l = blockIdx.z;
    const int n0 = blockIdx.x * 32, k0 = blockIdx.y * 32;
    const float* Wl = W + (size_t)l * K * N;
    ushortT* Hl = Thi + (size_t)l * K * N;
    ushortT* Ll = Tlo + (size_t)l * K * N;
    const int t = threadIdx.x;
    const int r = t >> 5, cc = t & 31;
#pragma unroll
    for (int q = 0; q < 4; q++)
        tile[r + q * 8][cc] = Wl[(size_t)(k0 + r + q * 8) * N + n0 + cc];
    __syncthreads();
#pragma unroll
    for (int q = 0; q < 4; q++) {
        const int nl = r + q * 8, kl = cc;
        const float v = tile[kl][nl];
        const ushortT hi = f2bf(v);
        Hl[(size_t)(n0 + nl) * K + k0 + kl] = hi;
        Ll[(size_t)(n0 + nl) * K + k0 + kl] = f2bf(v - bf2f(hi));
    }
}

// ---------------------------------------------------------------------------
// Unified split-bf16 MFMA GEMM (r8 proven).
// ---------------------------------------------------------------------------
template<int K, int N, int TM, bool RELU, int IN_MODE, int OUT_MODE>
__global__ __launch_bounds__(256) void k_mgemm(const ushortT* __restrict__ Ahi,
                                               const ushortT* __restrict__ Alo,
                                               const float* __restrict__ Afp,
                                               const ushortT* __restrict__ BThi,
                                               const ushortT* __restrict__ BTlo,
                                               float* __restrict__ Yf,
                                               ushortT* __restrict__ O1,
                                               ushortT* __restrict__ O2) {
    constexpr int MF = TM / 16;
    constexpr int NW = N / 4;
    constexpr int NF = NW / 16;
    constexpr int SSTG = (TM + N) * 160;
    constexpr int SEPI = TM * (N + 8) * 4;
    constexpr int SMEM = SSTG > SEPI ? SSTG : SEPI;
    __shared__ char smem[SMEM];
    ushortT* sAhi = (ushortT*)smem;
    ushortT* sAlo = sAhi + TM * 40;
    ushortT* sBhi = sAlo + TM * 40;
    ushortT* sBlo = sBhi + (size_t)N * 40;
    const int t = threadIdx.x;
    const int wave = t >> 6, lane = t & 63;
    const int lrow = lane & 15, lg = lane >> 4;
    const int row0 = blockIdx.x * TM;

    f32x4 acc[MF][NF];
#pragma unroll
    for (int m = 0; m < MF; m++)
#pragma unroll
        for (int n = 0; n < NF; n++) {
            acc[m][n][0]=0.f; acc[m][n][1]=0.f; acc[m][n][2]=0.f; acc[m][n][3]=0.f;
        }

    for (int k0 = 0; k0 < K; k0 += 32) {
        __syncthreads();
        if (IN_MODE == 2) {
#pragma unroll
            for (int p = 0; p < TM * 8 / 256; p++) {
                const int idx = t + p * 256;
                const int row = idx >> 3, cu = (idx & 7) * 4;
                const float4 v = *(const float4*)&Afp[(size_t)(row0 + row) * K + k0 + cu];
                ushort4 hi, lo;
                hi.x = f2bf(v.x); lo.x = f2bf(v.x - bf2f(hi.x));
                hi.y = f2bf(v.y); lo.y = f2bf(v.y - bf2f(hi.y));
                hi.z = f2bf(v.z); lo.z = f2bf(v.z - bf2f(hi.z));
                hi.w = f2bf(v.w); lo.w = f2bf(v.w - bf2f(hi.w));
                *(ushort4*)&sAhi[row * 40 + cu] = hi;
                *(ushort4*)&sAlo[row * 40 + cu] = lo;
            }
        } else {
#pragma unroll
            for (int p = 0; p < TM * 8 / 256; p++) {
                const int idx = t + p * 256;
                const bool ishi = idx < TM * 4;
                const int i2 = ishi ? idx : idx - TM * 4;
                const int row = i2 >> 2, cu = (i2 & 3) * 8;
                size_t ga;
                if (IN_MODE == 0) {
                    ga = (size_t)(row0 + row) * K + k0 + cu;
                } else {
                    const int m = row0 + row;
                    const int b = m >> 10, n = m & 1023;
                    const int hh = k0 >> 7, d = (k0 & 127) + cu;
                    ga = (((size_t)(b * 2 + hh) << 10) + n) * DD + d;
                }
                const ushortT* src = ishi ? Ahi : Alo;
                ushortT* dst = ishi ? sAhi : sAlo;
                *(uint4*)&dst[row * 40 + cu] = *(const uint4*)&src[ga];
            }
        }
#pragma unroll
        for (int p = 0; p < N / 32; p++) {
            const int idx = t + p * 256;
            const bool ishi = idx < N * 4;
            const int i2 = ishi ? idx : idx - N * 4;
            const int row = i2 >> 2, cu = (i2 & 3) * 8;
            const ushortT* src = ishi ? BThi : BTlo;
            ushortT* dst = ishi ? sBhi : sBlo;
            *(uint4*)&dst[row * 40 + cu] = *(const uint4*)&src[(size_t)row * K + k0 + cu];
        }
        __syncthreads();
        bf16x8 a0[MF], a1[MF], b0[NF], b1[NF];
#pragma unroll
        for (int m = 0; m < MF; m++) {
            const int off = (m * 16 + lrow) * 40 + lg * 8;
            a0[m] = *(const bf16x8*)&sAhi[off];
            a1[m] = *(const bf16x8*)&sAlo[off];
        }
#pragma unroll
        for (int n = 0; n < NF; n++) {
            const int off = (wave * NW + n * 16 + lrow) * 40 + lg * 8;
            b0[n] = *(const bf16x8*)&sBhi[off];
            b1[n] = *(const bf16x8*)&sBlo[off];
        }
#pragma unroll
        for (int m = 0; m < MF; m++)
#pragma unroll
            for (int n = 0; n < NF; n++) {
                acc[m][n] = __builtin_amdgcn_mfma_f32_16x16x32_bf16(a0[m], b0[n], acc[m][n], 0, 0, 0);
                acc[m][n] = __builtin_amdgcn_mfma_f32_16x16x32_bf16(a0[m], b1[n], acc[m][n], 0, 0, 0);
                acc[m][n] = __builtin_amdgcn_mfma_f32_16x16x32_bf16(a1[m], b0[n], acc[m][n], 0, 0, 0);
            }
    }

    __syncthreads();
    float* tile = (float*)smem;
#pragma unroll
    for (int m = 0; m < MF; m++)
#pragma unroll
        for (int n = 0; n < NF; n++) {
            const int col = wave * NW + n * 16 + lrow;
#pragma unroll
            for (int q = 0; q < 4; q++)
                tile[(m * 16 + lg * 4 + q) * (N + 8) + col] = acc[m][n][q];
        }
    __syncthreads();
#pragma unroll
    for (int p = 0; p < TM * N / 1024; p++) {
        const int idx = t + p * 256;
        const int row = idx / (N / 4), cg = idx % (N / 4);
        float4 v = *(const float4*)&tile[row * (N + 8) + cg * 4];
        if (RELU) {
            v.x = fmaxf(v.x, 0.f); v.y = fmaxf(v.y, 0.f);
            v.z = fmaxf(v.z, 0.f); v.w = fmaxf(v.w, 0.f);
        }
        const int m = row0 + row;
        if (OUT_MODE == 0) {
            *(float4*)&Yf[(size_t)m * N + cg * 4] = v;
        } else {
            ushort4 hi, lo;
            hi.x = f2bf(v.x); lo.x = f2bf(v.x - bf2f(hi.x));
            hi.y = f2bf(v.y); lo.y = f2bf(v.y - bf2f(hi.y));
            hi.z = f2bf(v.z); lo.z = f2bf(v.z - bf2f(hi.z));
            hi.w = f2bf(v.w); lo.w = f2bf(v.w - bf2f(hi.w));
            if (OUT_MODE == 1) {
                const int b = m >> 10, n = m & 1023;
                const int col = cg * 4;
                const int hh = col >> 7, d = col & 127;
                const size_t addr = (((size_t)(b * 2 + hh) << 10) + n) * DD + d;
                *(float4*)&Yf[addr] = v;
                *(ushort4*)&O1[addr] = hi;
                *(ushort4*)&O2[addr] = lo;
            } else {
                const size_t addr = (size_t)m * N + cg * 4;
                if (OUT_MODE == 3) *(float4*)&Yf[addr] = v;
                *(ushort4*)&O1[addr] = hi;
                *(ushort4*)&O2[addr] = lo;
            }
        }
    }
}

// ---------------------------------------------------------------------------
// e = sym MFMA (r7 proven: f16 e, upper-tri, coalesced dual write, XCD swz)
// ---------------------------------------------------------------------------
__global__ __launch_bounds__(256) void k_esym_mfma(const ushortT* __restrict__ wHi,
                                                   const ushortT* __restrict__ wLo,
                                                   const ushortT* __restrict__ hHi,
                                                   const ushortT* __restrict__ hLo,
                                                   ushortT* __restrict__ e) {
    __shared__ ushortT smem[20480];
    ushortT* sWjHi = smem;
    ushortT* sWjLo = smem + 2560;
    ushortT* sHjHi = smem + 5120;
    ushortT* sHjLo = smem + 7680;
    ushortT* sWkHi = smem + 10240;
    ushortT* sWkLo = smem + 12800;
    ushortT* sHkHi = smem + 15360;
    ushortT* sHkLo = smem + 17920;

    const int wgid = blockIdx.x;
    const int flat = (wgid & 7) * 272 + (wgid >> 3);
    const int bh = flat / 136;
    int idx = flat % 136, tj = 0;
    while (idx >= 16 - tj) { idx -= 16 - tj; tj++; }
    const int tk = tj + idx;
    const int j0 = tj * 64, k0 = tk * 64;
    const int t = threadIdx.x;
    const int wave = t >> 6, lane = t & 63;
    const int wr = wave >> 1, wc = wave & 1;
    const int lrow = lane & 15, lg = lane >> 4;

    f32x4 acc[2][2];
#pragma unroll
    for (int m = 0; m < 2; m++)
#pragma unroll
        for (int n = 0; n < 2; n++) {
            acc[m][n][0] = 0.f; acc[m][n][1] = 0.f;
            acc[m][n][2] = 0.f; acc[m][n][3] = 0.f;
        }

    const size_t bhbase = (size_t)bh * NN * DD;

    for (int d0 = 0; d0 < DD; d0 += 32) {
        __syncthreads();
        {
            const int row = t >> 2, cu = (t & 3) * 8;
#define STAGE1(SRC, DST, BASE)                                                    \
            *(uint4*)&DST[row * 40 + cu] =                                        \
                *(const uint4*)&SRC[bhbase + (size_t)(BASE + row) * DD + d0 + cu];
            STAGE1(wHi, sWjHi, j0) STAGE1(wLo, sWjLo, j0)
            STAGE1(hHi, sHjHi, j0) STAGE1(hLo, sHjLo, j0)
            STAGE1(wHi, sWkHi, k0) STAGE1(wLo, sWkLo, k0)
            STAGE1(hHi, sHkHi, k0) STAGE1(hLo, sHkLo, k0)
#undef STAGE1
        }
        __syncthreads();

        bf16x8 a0[2], a1[2], b0[2], b1[2];
#pragma unroll
        for (int m = 0; m < 2; m++) {
            const int off = (wr * 32 + m * 16 + lrow) * 40 + lg * 8;
            a0[m] = *(const bf16x8*)&sWjHi[off];
            a1[m] = *(const bf16x8*)&sWjLo[off];
        }
#pragma unroll
        for (int n = 0; n < 2; n++) {
            const int off = (wc * 32 + n * 16 + lrow) * 40 + lg * 8;
            b0[n] = *(const bf16x8*)&sHkHi[off];
            b1[n] = *(const bf16x8*)&sHkLo[off];
        }
#pragma unroll
        for (int m = 0; m < 2; m++)
#pragma unroll
            for (int n = 0; n < 2; n++) {
                acc[m][n] = __builtin_amdgcn_mfma_f32_16x16x32_bf16(a0[m], b0[n], acc[m][n], 0, 0, 0);
                acc[m][n] = __builtin_amdgcn_mfma_f32_16x16x32_bf16(a0[m], b1[n], acc[m][n], 0, 0, 0);
                acc[m][n] = __builtin_amdgcn_mfma_f32_16x16x32_bf16(a1[m], b0[n], acc[m][n], 0, 0, 0);
            }
#pragma unroll
        for (int m = 0; m < 2; m++) {
            const int off = (wr * 32 + m * 16 + lrow) * 40 + lg * 8;
            a0[m] = *(const bf16x8*)&sHjHi[off];
            a1[m] = *(const bf16x8*)&sHjLo[off];
        }
#pragma unroll
        for (int n = 0; n < 2; n++) {
            const int off = (wc * 32 + n * 16 + lrow) * 40 + lg * 8;
            b0[n] = *(const bf16x8*)&sWkHi[off];
            b1[n] = *(const bf16x8*)&sWkLo[off];
        }
#pragma unroll
        for (int m = 0; m < 2; m++)
#pragma unroll
            for (int n = 0; n < 2; n++) {
                acc[m][n] = __builtin_amdgcn_mfma_f32_16x16x32_bf16(a0[m], b0[n], acc[m][n], 0, 0, 0);
                acc[m][n] = __builtin_amdgcn_mfma_f32_16x16x32_bf16(a0[m], b1[n], acc[m][n], 0, 0, 0);
                acc[m][n] = __builtin_amdgcn_mfma_f32_16x16x32_bf16(a1[m], b0[n], acc[m][n], 0, 0, 0);
            }
    }

    __syncthreads();
    ushortT* tileN = smem;
    ushortT* tileT = smem + 4608;
#pragma unroll
    for (int m = 0; m < 2; m++)
#pragma unroll
        for (int n = 0; n < 2; n++) {
            const int jlb = wr * 32 + m * 16 + lg * 4;
            const int kl  = wc * 32 + n * 16 + lrow;
            ushort4 tv;
            tv.x = f2h(acc[m][n][0]); tv.y = f2h(acc[m][n][1]);
            tv.z = f2h(acc[m][n][2]); tv.w = f2h(acc[m][n][3]);
            tileN[(jlb + 0) * 72 + kl] = tv.x;
            tileN[(jlb + 1) * 72 + kl] = tv.y;
            tileN[(jlb + 2) * 72 + kl] = tv.z;
            tileN[(jlb + 3) * 72 + kl] = tv.w;
            *(ushort4*)&tileT[kl * 72 + jlb] = tv;
        }
    __syncthreads();
#pragma unroll
    for (int it = 0; it < 4; it++) {
        const int i2 = t + it * 256;
        const int row = i2 >> 4, ch = (i2 & 15) * 4;
        *(uint2*)&e[((size_t)bh * NN + j0 + row) * NN + k0 + ch] =
            *(const uint2*)&tileN[row * 72 + ch];
        if (tj != tk)
            *(uint2*)&e[((size_t)bh * NN + k0 + row) * NN + j0 + ch] =
                *(const uint2*)&tileT[row * 72 + ch];
    }
}

// ---------------------------------------------------------------------------
__global__ __launch_bounds__(256) void k_buildT(const float* __restrict__ adj,
                                                u64* __restrict__ bits) {
    const int gid = blockIdx.x * 256 + threadIdx.x;
    const int k  = gid & 1023;
    const int tw = (gid >> 10) & 15;
    const int b  = gid >> 14;
    const float* ac = adj + ((size_t)b << 20) + k;
    u64 w = 0;
#pragma unroll 8
    for (int jj = 0; jj < 64; jj++) {
        if (ac[(size_t)(tw * 64 + jj) << 10] != 0.f) w |= 1ull << jj;
    }
    bits[((size_t)((b << 10) | k)) * 16 + tw] = w;
}

__global__ __launch_bounds__(256) void k_cnt(const u64* __restrict__ bits,
                                             int* __restrict__ ccnt) {
    const int gid = blockIdx.x * 256 + threadIdx.x;
    const u64* wb = bits + (size_t)gid * 16;
    int c = 0;
#pragma unroll
    for (int tw = 0; tw < 16; tw++) c += __popcll(wb[tw]);
    ccnt[gid] = c;
}

// ---------------------------------------------------------------------------
__global__ __launch_bounds__(256) void k_smA(const ushortT* __restrict__ e,
                                             const u64* __restrict__ bits,
                                             float* __restrict__ pm,
                                             float* __restrict__ ps) {
    const int gid = blockIdx.x * 256 + threadIdx.x;
    const int kg = gid & 255;
    const int jc = (gid >> 8) & 63;
    const int bh = gid >> 14;
    const int b  = bh >> 1;
    const int k4 = kg * 4;
    const int tw = jc >> 2;
    const int bo = (jc & 3) * 16;
    u64 w[4];
#pragma unroll
    for (int i = 0; i < 4; i++)
        w[i] = bits[((size_t)((b << 10) | (k4 + i))) * 16 + tw];
    const ushortT* ec = e + ((size_t)bh << 20) + (size_t)(jc * 16) * NN + k4;
    float m[4] = {0.f, 0.f, 0.f, 0.f};
    float s[4] = {0.f, 0.f, 0.f, 0.f};
#pragma unroll
    for (int r = 0; r < 16; r++) {
        const ushort4 ev = *(const ushort4*)&ec[(size_t)r * NN];
        const float evs[4] = {h2f(ev.x), h2f(ev.y), h2f(ev.z), h2f(ev.w)};
#pragma unroll
        for (int i = 0; i < 4; i++) {
            const bool on = (w[i] >> (bo + r)) & 1;
            const float v = on ? evs[i] : 0.f;
            const float mn = fmaxf(m[i], v);
            s[i] = s[i] * __expf(m[i] - mn) + (on ? __expf(v - mn) : 0.f);
            m[i] = mn;
        }
    }
    const size_t o = (((size_t)bh * 64 + jc) << 10) + k4;
    *(float4*)&pm[o] = make_float4(m[0], m[1], m[2], m[3]);
    *(float4*)&ps[o] = make_float4(s[0], s[1], s[2], s[3]);
}

__global__ __launch_bounds__(256) void k_smB(const float* __restrict__ pm,
                                             const float* __restrict__ ps,
                                             const int* __restrict__ ccnt,
                                             float* __restrict__ smax,
                                             float* __restrict__ sdinv) {
    __shared__ float lm[4][64], ls[4][64];
    const int t = threadIdx.x, q = t >> 6, lane = t & 63;
    const int colg = blockIdx.x * 64 + lane;
    const int bh = colg >> 10, k = colg & 1023;
    const int b  = bh >> 1;
    float M = 0.f, S = 0.f;
#pragma unroll 4
    for (int i = 0; i < 16; i++) {
        const int jc = q * 16 + i;
        const size_t o = (((size_t)bh * 64 + jc) << 10) + k;
        const float pmv = pm[o], psv = ps[o];
        const float mn = fmaxf(M, pmv);
        S = S * __expf(M - mn) + psv * __expf(pmv - mn);
        M = mn;
    }
    lm[q][lane] = M; ls[q][lane] = S;
    __syncthreads();
    if (q == 0) {
#pragma unroll
        for (int qq = 1; qq < 4; qq++) {
            const float pmv = lm[qq][lane], psv = ls[qq][lane];
            const float mn = fmaxf(M, pmv);
            S = S * __expf(M - mn) + psv * __expf(pmv - mn);
            M = mn;
        }
        S += (float)(NN - ccnt[(b << 10) + k]) * __expf(-M);
        smax[colg] = M;
        sdinv[colg] = 1.f / S;
    }
}

__global__ __launch_bounds__(256) void k_smC(const ushortT* __restrict__ e,
                                             const u64* __restrict__ bits,
                                             const float* __restrict__ smax,
                                             const float* __restrict__ sdinv,
                                             ushortT* __restrict__ att) {
    const int gid = blockIdx.x * 256 + threadIdx.x;
    const int kg = gid & 255;
    const int jc = (gid >> 8) & 63;
    const int bh = gid >> 14;
    const int b  = bh >> 1;
    const int k4 = kg * 4;
    const int tw = jc >> 2;
    const int bo = (jc & 3) * 16;
    u64 w[4];
#pragma unroll
    for (int i = 0; i < 4; i++)
        w[i] = bits[((size_t)((b << 10) | (k4 + i))) * 16 + tw];
    const float4 m4 = *(const float4*)&smax[(bh << 10) + k4];
    const float4 d4 = *(const float4*)&sdinv[(bh << 10) + k4];
    const float ms[4] = {m4.x, m4.y, m4.z, m4.w};
    const float ds[4] = {d4.x, d4.y, d4.z, d4.w};
    const ushortT* ec = e + ((size_t)bh << 20) + (size_t)(jc * 16) * NN + k4;
    ushortT* ac = att + ((size_t)bh << 20) + (size_t)(jc * 16) * NN + k4;
#pragma unroll
    for (int r = 0; r < 16; r++) {
        const ushort4 ev = *(const ushort4*)&ec[(size_t)r * NN];
        const float evs[4] = {h2f(ev.x), h2f(ev.y), h2f(ev.z), h2f(ev.w)};
        ushort4 o;
        ushortT os[4];
#pragma unroll
        for (int i = 0; i < 4; i++) {
            const bool on = (w[i] >> (bo + r)) & 1;
            os[i] = f2h(on ? __expf(evs[i] - ms[i]) * ds[i] : 0.f);
        }
        o.x = os[0]; o.y = os[1]; o.z = os[2]; o.w = os[3];
        *(ushort4*)&ac[(size_t)r * NN] = o;
    }
}

// ---------------------------------------------------------------------------
__global__ __launch_bounds__(256) void k_trT(const float* __restrict__ h,
                                             ushortT* __restrict__ hT) {
    __shared__ float tile[64][65];
    const int bh = blockIdx.z;
    const int n0 = blockIdx.x * 64, d0 = blockIdx.y * 64;
    const int t = threadIdx.x;
#pragma unroll
    for (int q = 0; q < 16; q++) {
        const int idx = t + q * 256;
        const int row = idx >> 6, col = idx & 63;
        tile[row][col] = h[(size_t)bh * 131072 + (size_t)(n0 + row) * DD + d0 + col];
    }
    __syncthreads();
#pragma unroll
    for (int q = 0; q < 16; q++) {
        const int idx = t + q * 256;
        const int row = idx >> 6, col = idx & 63;
        hT[(size_t)bh * 131072 + (size_t)(d0 + row) * NN + n0 + col] = f2h(tile[col][row]);
    }
}

// z (mixed, f16 [bh][d][n]) -> relu + bf16 hi/lo split [bh][n][d]
__global__ __launch_bounds__(256) void k_fin(const ushortT* __restrict__ zT,
                                             ushortT* __restrict__ zHi,
                                             ushortT* __restrict__ zLo) {
    __shared__ float tile[64][65];
    const int bh = blockIdx.z;
    const int n0 = blockIdx.x * 64, d0 = blockIdx.y * 64;
    const int t = threadIdx.x;
#pragma unroll
    for (int q = 0; q < 16; q++) {
        const int idx = t + q * 256;
        const int row = idx >> 6, col = idx & 63;
        tile[row][col] = h2f(zT[(size_t)bh * 131072 + (size_t)(d0 + row) * NN + n0 + col]);
    }
    __syncthreads();
#pragma unroll
    for (int q = 0; q < 16; q++) {
        const int idx = t + q * 256;
        const int row = idx >> 6, col = idx & 63;
        const float v = fmaxf(tile[col][row], 0.f);
        const ushortT hi = f2bf(v);
        const size_t addr = (size_t)bh * 131072 + (size_t)(n0 + row) * DD + d0 + col;
        zHi[addr] = hi;
        zLo[addr] = f2bf(v - bf2f(hi));
    }
}

// ---------------------------------------------------------------------------
// Dense f16 MFMA hop, 8 waves, j-chunk 128, XCD swizzle. Both modes write
// MIXED z_{t+1} = beta*h + (1-beta)*relu(att@zin) in the epilogue (once).
// MODE 0: zin = hT; beta computed in-block first (az stashed to LDS).
// MODE 1: zin = previous mixed z; beta read from global (r8-proven FUSED).
// ---------------------------------------------------------------------------
template<int MODE>
__global__ __launch_bounds__(512) void k_hop(const ushortT* __restrict__ att,
                                             const ushortT* __restrict__ zin,
                                             const ushortT* __restrict__ hT,
                                             float* __restrict__ beta,
                                             const float* __restrict__ Wbw,
                                             const float* __restrict__ Wbb,
                                             ushortT* __restrict__ zout) {
    __shared__ ushortT smem[64 * 136 + 128 * 136];
    ushortT* sA = smem;                         // [64][136]
    ushortT* sB = smem + 64 * 136;              // [128][136]
    const int bid = blockIdx.x;                 // 256 = 8 XCD x 32
    const int flat = (bid & 7) * 32 + (bid >> 3);
    const int bh = flat >> 4;
    const int i0 = (flat & 15) * 64;
    const int t = threadIdx.x, wave = t >> 6, lane = t & 63;
    const int wr = wave >> 2, wc = wave & 3;
    const int lrow = lane & 15, lg = lane >> 4;
    const ushortT* attb = att + ((size_t)bh << 20);
    const ushortT* hTb  = hT + (size_t)bh * 131072;
    const ushortT* zb   = (MODE == 0) ? hTb : zin + (size_t)bh * 131072;

    f32x4 acc[2][2];
#pragma unroll
    for (int m = 0; m < 2; m++)
#pragma unroll
        for (int n = 0; n < 2; n++) {
            acc[m][n][0]=0.f; acc[m][n][1]=0.f; acc[m][n][2]=0.f; acc[m][n][3]=0.f;
        }

    for (int j0 = 0; j0 < NN; j0 += 128) {
        __syncthreads();
#pragma unroll
        for (int q = 0; q < 2; q++) {           // sA: 64x128 = 1024 uint4
            const int u = t + q * 512;
            const int row = u >> 4, c8 = (u & 15) * 8;
            *(uint4*)&sA[row * 136 + c8] =
                *(const uint4*)&attb[(size_t)(i0 + row) * NN + j0 + c8];
        }
#pragma unroll
        for (int q = 0; q < 4; q++) {           // sB: 128x128 = 2048 uint4
            const int u = t + q * 512;
            const int row = u >> 4, c8 = (u & 15) * 8;
            *(uint4*)&sB[row * 136 + c8] =
                *(const uint4*)&zb[(size_t)row * NN + j0 + c8];
        }
        __syncthreads();
#pragma unroll
        for (int ks = 0; ks < 4; ks++) {
            f16x8 a[2], b[2];
#pragma unroll
            for (int m = 0; m < 2; m++)
                a[m] = *(const f16x8*)&sA[(wr * 32 + m * 16 + lrow) * 136 + ks * 32 + lg * 8];
#pragma unroll
            for (int n = 0; n < 2; n++)
                b[n] = *(const f16x8*)&sB[(wc * 32 + n * 16 + lrow) * 136 + ks * 32 + lg * 8];
#pragma unroll
            for (int m = 0; m < 2; m++)
#pragma unroll
                for (int n = 0; n < 2; n++)
                    acc[m][n] = __builtin_amdgcn_mfma_f32_16x16x32_f16(a[m], b[n], acc[m][n], 0, 0, 0);
        }
    }

    ushortT* zo = zout + (size_t)bh * 131072;

    if (MODE == 1) {
        // r8-proven FUSED epilogue: mix with global beta, write mixed z
        const float* betab = beta + ((size_t)bh << 10);
#pragma unroll
        for (int m = 0; m < 2; m++)
#pragma unroll
            for (int n = 0; n < 2; n++) {
                const int d = wc * 32 + n * 16 + lrow;
                const int i = i0 + wr * 32 + m * 16 + lg * 4;
                const float4 bev = *(const float4*)&betab[i];
                const ushort4 hv = *(const ushort4*)&hTb[(size_t)d * NN + i];
                ushort4 o;
                o.x = f2h(bev.x * h2f(hv.x) + (1.f - bev.x) * fmaxf(acc[m][n][0], 0.f));
                o.y = f2h(bev.y * h2f(hv.y) + (1.f - bev.y) * fmaxf(acc[m][n][1], 0.f));
                o.z = f2h(bev.z * h2f(hv.z) + (1.f - bev.z) * fmaxf(acc[m][n][2], 0.f));
                o.w = f2h(bev.w * h2f(hv.w) + (1.f - bev.w) * fmaxf(acc[m][n][3], 0.f));
                *(ushort4*)&zo[(size_t)d * NN + i] = o;
            }
    } else {
        // ---- MODE 0: compute beta in-block, then write mixed z1 ----
        ushort4 ofrag[2][2];
#pragma unroll
        for (int m = 0; m < 2; m++)
#pragma unroll
            for (int n = 0; n < 2; n++) {
                ushort4 o;
                o.x = f2h(fmaxf(acc[m][n][0], 0.f));
                o.y = f2h(fmaxf(acc[m][n][1], 0.f));
                o.z = f2h(fmaxf(acc[m][n][2], 0.f));
                o.w = f2h(fmaxf(acc[m][n][3], 0.f));
                ofrag[m][n] = o;
            }
        __syncthreads();                        // staging LDS dead; reuse
        ushortT* azl = smem;                    // [128][72]
        ushortT* hl  = smem + 128 * 72;         // [128][72]
        float*   bl  = (float*)(smem + 2 * 128 * 72);  // [64]
#pragma unroll
        for (int m = 0; m < 2; m++)
#pragma unroll
            for (int n = 0; n < 2; n++) {
                const int d = wc * 32 + n * 16 + lrow;
                const int il = wr * 32 + m * 16 + lg * 4;
                const ushort4 o = ofrag[m][n];
                azl[d * 72 + il + 0] = o.x;
                azl[d * 72 + il + 1] = o.y;
                azl[d * 72 + il + 2] = o.z;
                azl[d * 72 + il + 3] = o.w;
            }
#pragma unroll
        for (int q = 0; q < 2; q++) {           // hl: 128 rows x 64 cols
            const int u = t + q * 512;
            const int row = u >> 3, c8 = (u & 7) * 8;
            *(uint4*)&hl[row * 72 + c8] =
                *(const uint4*)&hTb[(size_t)row * NN + i0 + c8];
        }
        __syncthreads();
        {
            const int i = t >> 3, c = t & 7;    // i: 0..63, c: d-chunk 0..7
            float p = 0.f;
#pragma unroll
            for (int dd = 0; dd < 16; dd++) {
                const int d = c * 16 + dd;
                p += h2f(hl[d * 72 + i]) * Wbw[d] + h2f(azl[d * 72 + i]) * Wbw[DD + d];
            }
            p += __shfl_down(p, 4, 8);
            p += __shfl_down(p, 2, 8);
            p += __shfl_down(p, 1, 8);
            if (c == 0) {
                const float be = 1.f / (1.f + expf(-(p + Wbb[0])));
                beta[(bh << 10) + i0 + i] = be;
                bl[i] = be;
            }
        }
        __syncthreads();
#pragma unroll
        for (int m = 0; m < 2; m++)
#pragma unroll
            for (int n = 0; n < 2; n++) {
                const int d = wc * 32 + n * 16 + lrow;
                const int il = wr * 32 + m * 16 + lg * 4;
                const ushort4 az = ofrag[m][n];
                ushort4 o;
                o.x = f2h(bl[il+0] * h2f(hl[d*72+il+0]) + (1.f - bl[il+0]) * h2f(az.x));
                o.y = f2h(bl[il+1] * h2f(hl[d*72+il+1]) + (1.f - bl[il+1]) * h2f(az.y));
                o.z = f2h(bl[il+2] * h2f(hl[d*72+il+2]) + (1.f - bl[il+2]) * h2f(az.z));
                o.w = f2h(bl[il+3] * h2f(hl[d*72+il+3]) + (1.f - bl[il+3]) * h2f(az.w));
                *(ushort4*)&zo[(size_t)d * NN + i0 + il] = o;
            }
    }
}

// c = c2 - c1 fp32 + bf16 hi/lo split
__global__ __launch_bounds__(256) void k_sub(const float* __restrict__ c2,
                                             const float* __restrict__ c1,
                                             float* __restrict__ c,
                                             ushortT* __restrict__ cHi,
                                             ushortT* __restrict__ cLo) {
    const int g = blockIdx.x * 256 + threadIdx.x;
    const float4 a = ((const float4*)c2)[g];
    const float4 b = ((const float4*)c1)[g];
    const float4 v = make_float4(a.x - b.x, a.y - b.y, a.z - b.z, a.w - b.w);
    ((float4*)c)[g] = v;
    ushort4 hi, lo;
    hi.x = f2bf(v.x); lo.x = f2bf(v.x - bf2f(hi.x));
    hi.y = f2bf(v.y); lo.y = f2bf(v.y - bf2f(hi.y));
    hi.z = f2bf(v.z); lo.z = f2bf(v.z - bf2f(hi.z));
    hi.w = f2bf(v.w); lo.w = f2bf(v.w - bf2f(hi.w));
    ((ushort4*)cHi)[g] = hi;
    ((ushort4*)cLo)[g] = lo;
}

__global__ __launch_bounds__(128) void k_poolA(const float* __restrict__ c,
                                               const float* __restrict__ valid,
                                               float* __restrict__ pp,
                                               float* __restrict__ pv) {
    const int bc = blockIdx.x;
    const int b = bc >> 4, ch = bc & 15;
    const int d = threadIdx.x;
    const float* cb = c + ((size_t)b << 17) + (size_t)(ch * 64) * DD;
    const float* vb = valid + (b << 10) + ch * 64;
    float s = 0.f, sv = 0.f;
#pragma unroll 8
    for (int i = 0; i < 64; i++) { const float v = vb[i]; s += cb[(size_t)i * DD + d] * v; sv += v; }
    pp[bc * 128 + d] = s;
    if (d == 0) pv[bc] = sv;
}

__global__ __launch_bounds__(256) void k_poolB(const float* __restrict__ pp,
                                               const float* __restrict__ pv,
                                               float* __restrict__ pooled) {
    const int gid = blockIdx.x * 256 + threadIdx.x;
    const int b = gid >> 7, d = gid & 127;
    float s = 0.f, sv = 0.f;
#pragma unroll
    for (int ch = 0; ch < 16; ch++) {
        s  += pp[(b * 16 + ch) * 128 + d];
        sv += pv[b * 16 + ch];
    }
    pooled[b * 128 + d] = s / sv;
}

template<int K, int NOUT, bool RELU>
__global__ void k_fc(const float* __restrict__ X, const float* __restrict__ W,
                     const float* __restrict__ bias, float* __restrict__ Y) {
    const int gid = blockIdx.x * blockDim.x + threadIdx.x;
    if (gid >= BB * NOUT) return;
    const int b = gid / NOUT, o = gid % NOUT;
    float s = bias[o];
    for (int i = 0; i < K; i++) s += X[(size_t)b * K + i] * W[(size_t)i * NOUT + o];
    Y[gid] = RELU ? fmaxf(s, 0.f) : s;
}

__global__ void k_fc2(const float* __restrict__ X, const float* __restrict__ W,
                      const float* __restrict__ bias, float* __restrict__ out) {
    const int b = threadIdx.x >> 6, lane = threadIdx.x & 63;
    float s = 0.f;
    for (int i = lane; i < DFCN; i += 64) s += X[(size_t)b * DFCN + i] * W[i];
#pragma unroll
    for (int off = 32; off > 0; off >>= 1) s += __shfl_down(s, off);
    if (lane == 0) out[b] = 1.f / (1.f + expf(-(s + bias[0])));
}

// ---------------------------------------------------------------------------
extern "C" void kernel_launch(void* const* d_in, const int* in_sizes, int n_in,
                              void* d_out, int out_size, void* d_ws, size_t ws_size,
                              hipStream_t stream) {
    const float* x        = (const float*)d_in[0];
    const float* adj1     = (const float*)d_in[1];
    const float* adj2     = (const float*)d_in[2];
    const float* valid    = (const float*)d_in[3];
    const float* embede_w = (const float*)d_in[4];
    const float* Wh       = (const float*)d_in[5];
    const float* We       = (const float*)d_in[6];
    const float* Wbw      = (const float*)d_in[7];
    const float* Wbb      = (const float*)d_in[8];
    const float* Wo       = (const float*)d_in[9];
    const float* fc0_w    = (const float*)d_in[10];
    const float* fc0_b    = (const float*)d_in[11];
    const float* fc1_w    = (const float*)d_in[12];
    const float* fc1_b    = (const float*)d_in[13];
    const float* fc2_w    = (const float*)d_in[14];
    const float* fc2_b    = (const float*)d_in[15];

    // ---- workspace carve ----
    float* ws = (float*)d_ws;
    float* c      = ws;                          // 1,048,576 f
    float* h      = c      + (size_t)1048576;    // 2,097,152 f
    float* c1     = h      + (size_t)2097152;    // 1,048,576 f
    float* c2     = c1     + (size_t)1048576;    // 1,048,576 f
    float* beta   = c2     + (size_t)1048576;    // 16,384 f
    float* pm     = beta   + (size_t)16384;      // 1,048,576 f
    float* ps     = pm     + (size_t)1048576;    // 1,048,576 f
    float* smax   = ps     + (size_t)1048576;    // 16,384 f
    float* sdinv  = smax   + (size_t)16384;      // 16,384 f
    float* pp     = sdinv  + (size_t)16384;      // 16,384 f
    float* pv     = pp     + (size_t)16384;      // 128 f
    float* pooled = pv     + (size_t)128;        // 1,024 f
    float* f0     = pooled + (size_t)1024;       // 4,096 f
    float* f1     = f0     + (size_t)4096;       // 4,096 f
    ushortT* hHi  = (ushortT*)(f1 + 4096);       // 2,097,152 us each
    ushortT* hLo  = hHi + (size_t)2097152;
    ushortT* wHi  = hLo + (size_t)2097152;
    ushortT* wLo  = wHi + (size_t)2097152;
    ushortT* hT   = wLo + (size_t)2097152;
    ushortT* zTa  = hT  + (size_t)2097152;
    ushortT* zTb  = zTa + (size_t)2097152;
    ushortT* cHi  = zTb + (size_t)2097152;       // 1,048,576 us each
    ushortT* cLo  = cHi + (size_t)1048576;
    ushortT* zHi  = cLo + (size_t)1048576;       // 2,097,152 us each
    ushortT* zLo  = zHi + (size_t)2097152;
    ushortT* att  = zLo + (size_t)2097152;       // 16,777,216 us
    ushortT* e    = att + (size_t)16777216;      // 16,777,216 us
    ushortT* WhTh = e   + (size_t)16777216;      // 131,072 us each
    ushortT* WhTl = WhTh + (size_t)131072;
    ushortT* WeTh = WhTl + (size_t)131072;       // 65,536 each
    ushortT* WeTl = WeTh + (size_t)65536;
    ushortT* WoTh = WeTl + (size_t)65536;        // 131,072 each
    ushortT* WoTl = WoTh + (size_t)131072;
    ushortT* EmTh = WoTl + (size_t)131072;       // 16,384 each
    ushortT* EmTl = EmTh + (size_t)16384;
    u64* bits1    = (u64*)(EmTl + (size_t)16384);
    u64* bits2    = bits1 + (size_t)131072;
    int* ccnt1    = (int*)(bits2 + (size_t)131072);
    int* ccnt2    = ccnt1 + 8192;

    // ---- one-time per launch: masks + weight splits ----
    k_buildT<<<512, 256, 0, stream>>>(adj1, bits1);
    k_buildT<<<512, 256, 0, stream>>>(adj2, bits2);
    k_cnt<<<32, 256, 0, stream>>>(bits1, ccnt1);
    k_cnt<<<32, 256, 0, stream>>>(bits2, ccnt2);
    k_splitWT<128,256><<<dim3(8,4,4), 256, 0, stream>>>(Wh, WhTh, WhTl);
    k_splitWT<128,128><<<dim3(4,4,4), 256, 0, stream>>>(We, WeTh, WeTl);
    k_splitWT<256,128><<<dim3(4,8,4), 256, 0, stream>>>(Wo, WoTh, WoTl);
    k_splitWT<128,128><<<dim3(4,4,1), 256, 0, stream>>>(embede_w, EmTh, EmTl);

    // c = x @ embede_w
    k_mgemm<128,128,32,false,2,3><<<256, 256, 0, stream>>>(
        nullptr, nullptr, x, EmTh, EmTl, c, cHi, cLo);

    for (int k = 0; k < LL; k++) {
        const int nhop = k + 1;
        const float* Wbw_k = Wbw + (size_t)k * 256;
        const float* Wbb_k = Wbb + k;
        // h = relu(c @ Wh[k]) -> scatter [bh][n][d] fp32 + splits
        k_mgemm<128,256,32,true,0,1><<<256, 256, 0, stream>>>(
            cHi, cLo, nullptr, WhTh + (size_t)k*32768, WhTl + (size_t)k*32768, h, hHi, hLo);
        // hW = h @ We[k] -> splits row-major
        k_mgemm<128,128,64,false,0,2><<<256, 256, 0, stream>>>(
            hHi, hLo, nullptr, WeTh + (size_t)k*16384, WeTl + (size_t)k*16384, nullptr, wHi, wLo);
        k_trT<<<dim3(16,2,16), 256, 0, stream>>>(h, hT);
        k_esym_mfma<<<2176, 256, 0, stream>>>(wHi, wLo, hHi, hLo, e);

        for (int br = 0; br < 2; br++) {
            const u64* bits = (br == 0) ? bits1 : bits2;
            const int* ccnt = (br == 0) ? ccnt1 : ccnt2;
            float*     cb   = (br == 0) ? c1    : c2;

            k_smA<<<1024, 256, 0, stream>>>(e, bits, pm, ps);
            k_smB<<<256, 256, 0, stream>>>(pm, ps, ccnt, smax, sdinv);
            k_smC<<<1024, 256, 0, stream>>>(e, bits, smax, sdinv, att);

            // hop0: beta in-block, writes mixed z1
            k_hop<0><<<256, 512, 0, stream>>>(att, nullptr, hT, beta, Wbw_k, Wbb_k, zTb);
            // hops 1..nhop-1: consume mixed z, write mixed z (epilogue mix, once)
            ushortT* zA = zTb; ushortT* zB = zTa;
            for (int tpp = 1; tpp < nhop; tpp++) {
                k_hop<1><<<256, 512, 0, stream>>>(att, zA, hT, beta, nullptr, nullptr, zB);
                ushortT* tmp = zA; zA = zB; zB = tmp;
            }
            // final: relu + split -> [n][d]; cb = relu(z) @ Wo[k]
            k_fin<<<dim3(16,2,16), 256, 0, stream>>>(zA, zHi, zLo);
            k_mgemm<256,128,32,false,1,0><<<256, 256, 0, stream>>>(
                zHi, zLo, nullptr, WoTh + (size_t)k*32768, WoTl + (size_t)k*32768, cb, nullptr, nullptr);
        }
        k_sub<<<1024, 256, 0, stream>>>(c2, c1, c, cHi, cLo);
    }

    k_poolA<<<128, 128, 0, stream>>>(c, valid, pp, pv);
    k_poolB<<<4, 256, 0, stream>>>(pp, pv, pooled);
    k_fc<128, DFCN, true><<<16, 256, 0, stream>>>(pooled, fc0_w, fc0_b, f0);
    k_fc<DFCN, DFCN, true><<<16, 256, 0, stream>>>(f0, fc1_w, fc1_b, f1);
    k_fc2<<<1, 512, 0, stream>>>(f1, fc2_w, fc2_b, (float*)d_out);
}

// Round 11
// 1055.503 us; speedup vs baseline: 1.1615x; 1.0421x over previous
//
#include <hip/hip_runtime.h>
#include <math.h>

#define BB 8
#define NN 1024
#define DD 128
#define HH 2
#define LL 4
#define DFCN 512

typedef __attribute__((ext_vector_type(8))) short bf16x8;
typedef __attribute__((ext_vector_type(8))) _Float16 f16x8;
typedef __attribute__((ext_vector_type(4))) float f32x4;
typedef unsigned long long u64;
typedef unsigned short ushortT;

static __device__ __forceinline__ unsigned short f2bf(float f) {
    unsigned u = __float_as_uint(f);
    u += 0x7FFF + ((u >> 16) & 1);
    return (unsigned short)(u >> 16);
}
static __device__ __forceinline__ float bf2f(unsigned short s) {
    return __uint_as_float(((unsigned)s) << 16);
}
static __device__ __forceinline__ unsigned short f2h(float f) {
    _Float16 h = (_Float16)f; return *(unsigned short*)&h;
}
static __device__ __forceinline__ float h2f(unsigned short u) {
    _Float16 h; *(unsigned short*)&h = u; return (float)h;
}

// ---------------------------------------------------------------------------
// Weight pre-split: W[l][k][n] fp32 -> WT hi/lo [l][n][k] bf16 (32x32 tiles)
// ---------------------------------------------------------------------------
template<int K, int N>
__global__ __launch_bounds__(256) void k_splitWT(const float* __restrict__ W,
                                                 ushortT* __restrict__ Thi,
                                                 ushortT* __restrict__ Tlo) {
    __shared__ float tile[32][33];
    const int l = blockIdx.z;
    const int n0 = blockIdx.x * 32, k0 = blockIdx.y * 32;
    const float* Wl = W + (size_t)l * K * N;
    ushortT* Hl = Thi + (size_t)l * K * N;
    ushortT* Ll = Tlo + (size_t)l * K * N;
    const int t = threadIdx.x;
    const int r = t >> 5, cc = t & 31;
#pragma unroll
    for (int q = 0; q < 4; q++)
        tile[r + q * 8][cc] = Wl[(size_t)(k0 + r + q * 8) * N + n0 + cc];
    __syncthreads();
#pragma unroll
    for (int q = 0; q < 4; q++) {
        const int nl = r + q * 8, kl = cc;
        const float v = tile[kl][nl];
        const ushortT hi = f2bf(v);
        Hl[(size_t)(n0 + nl) * K + k0 + kl] = hi;
        Ll[(size_t)(n0 + nl) * K + k0 + kl] = f2bf(v - bf2f(hi));
    }
}

// ---------------------------------------------------------------------------
// Unified split-bf16 MFMA GEMM.
// OUT_MODE 0: Yf fp32 row-major
//          1: scatter [bh][n][d] fp32 + splits
//          2: splits row-major only
//          3: Yf fp32 + splits row-major
//          4: scatter splits [bh][n][d] + hT f16 [bh][d][n] (Yf reused as hT;
//             no fp32 out) — fuses the old k_trT.
// ---------------------------------------------------------------------------
template<int K, int N, int TM, bool RELU, int IN_MODE, int OUT_MODE>
__global__ __launch_bounds__(256) void k_mgemm(const ushortT* __restrict__ Ahi,
                                               const ushortT* __restrict__ Alo,
                                               const float* __restrict__ Afp,
                                               const ushortT* __restrict__ BThi,
                                               const ushortT* __restrict__ BTlo,
                                               float* __restrict__ Yf,
                                               ushortT* __restrict__ O1,
                                               ushortT* __restrict__ O2) {
    constexpr int MF = TM / 16;
    constexpr int NW = N / 4;
    constexpr int NF = NW / 16;
    constexpr int SSTG = (TM + N) * 160;
    constexpr int SEPI = TM * (N + 8) * 4;
    constexpr int SMEM = SSTG > SEPI ? SSTG : SEPI;
    __shared__ char smem[SMEM];
    ushortT* sAhi = (ushortT*)smem;
    ushortT* sAlo = sAhi + TM * 40;
    ushortT* sBhi = sAlo + TM * 40;
    ushortT* sBlo = sBhi + (size_t)N * 40;
    const int t = threadIdx.x;
    const int wave = t >> 6, lane = t & 63;
    const int lrow = lane & 15, lg = lane >> 4;
    const int row0 = blockIdx.x * TM;

    f32x4 acc[MF][NF];
#pragma unroll
    for (int m = 0; m < MF; m++)
#pragma unroll
        for (int n = 0; n < NF; n++) {
            acc[m][n][0]=0.f; acc[m][n][1]=0.f; acc[m][n][2]=0.f; acc[m][n][3]=0.f;
        }

    for (int k0 = 0; k0 < K; k0 += 32) {
        __syncthreads();
        if (IN_MODE == 2) {
#pragma unroll
            for (int p = 0; p < TM * 8 / 256; p++) {
                const int idx = t + p * 256;
                const int row = idx >> 3, cu = (idx & 7) * 4;
                const float4 v = *(const float4*)&Afp[(size_t)(row0 + row) * K + k0 + cu];
                ushort4 hi, lo;
                hi.x = f2bf(v.x); lo.x = f2bf(v.x - bf2f(hi.x));
                hi.y = f2bf(v.y); lo.y = f2bf(v.y - bf2f(hi.y));
                hi.z = f2bf(v.z); lo.z = f2bf(v.z - bf2f(hi.z));
                hi.w = f2bf(v.w); lo.w = f2bf(v.w - bf2f(hi.w));
                *(ushort4*)&sAhi[row * 40 + cu] = hi;
                *(ushort4*)&sAlo[row * 40 + cu] = lo;
            }
        } else {
#pragma unroll
            for (int p = 0; p < TM * 8 / 256; p++) {
                const int idx = t + p * 256;
                const bool ishi = idx < TM * 4;
                const int i2 = ishi ? idx : idx - TM * 4;
                const int row = i2 >> 2, cu = (i2 & 3) * 8;
                size_t ga;
                if (IN_MODE == 0) {
                    ga = (size_t)(row0 + row) * K + k0 + cu;
                } else {
                    const int m = row0 + row;
                    const int b = m >> 10, n = m & 1023;
                    const int hh = k0 >> 7, d = (k0 & 127) + cu;
                    ga = (((size_t)(b * 2 + hh) << 10) + n) * DD + d;
                }
                const ushortT* src = ishi ? Ahi : Alo;
                ushortT* dst = ishi ? sAhi : sAlo;
                *(uint4*)&dst[row * 40 + cu] = *(const uint4*)&src[ga];
            }
        }
#pragma unroll
        for (int p = 0; p < N / 32; p++) {
            const int idx = t + p * 256;
            const bool ishi = idx < N * 4;
            const int i2 = ishi ? idx : idx - N * 4;
            const int row = i2 >> 2, cu = (i2 & 3) * 8;
            const ushortT* src = ishi ? BThi : BTlo;
            ushortT* dst = ishi ? sBhi : sBlo;
            *(uint4*)&dst[row * 40 + cu] = *(const uint4*)&src[(size_t)row * K + k0 + cu];
        }
        __syncthreads();
        bf16x8 a0[MF], a1[MF], b0[NF], b1[NF];
#pragma unroll
        for (int m = 0; m < MF; m++) {
            const int off = (m * 16 + lrow) * 40 + lg * 8;
            a0[m] = *(const bf16x8*)&sAhi[off];
            a1[m] = *(const bf16x8*)&sAlo[off];
        }
#pragma unroll
        for (int n = 0; n < NF; n++) {
            const int off = (wave * NW + n * 16 + lrow) * 40 + lg * 8;
            b0[n] = *(const bf16x8*)&sBhi[off];
            b1[n] = *(const bf16x8*)&sBlo[off];
        }
#pragma unroll
        for (int m = 0; m < MF; m++)
#pragma unroll
            for (int n = 0; n < NF; n++) {
                acc[m][n] = __builtin_amdgcn_mfma_f32_16x16x32_bf16(a0[m], b0[n], acc[m][n], 0, 0, 0);
                acc[m][n] = __builtin_amdgcn_mfma_f32_16x16x32_bf16(a0[m], b1[n], acc[m][n], 0, 0, 0);
                acc[m][n] = __builtin_amdgcn_mfma_f32_16x16x32_bf16(a1[m], b0[n], acc[m][n], 0, 0, 0);
            }
    }

    // OUT_MODE 4: emit hT f16 [bh][d][n] directly from frags (acc q-values are
    // 4 consecutive n -> natural ushort4; same write pattern as the hop zT).
    if (OUT_MODE == 4) {
        ushortT* hTp = (ushortT*)Yf;
        const int b = row0 >> 10;
        const int nb = row0 & 1023;
#pragma unroll
        for (int m = 0; m < MF; m++)
#pragma unroll
            for (int n = 0; n < NF; n++) {
                const int col = wave * NW + n * 16 + lrow;
                const int hh = col >> 7, d = col & 127;
                const int nn = nb + m * 16 + lg * 4;
                ushort4 o;
                o.x = f2h(fmaxf(acc[m][n][0], 0.f));
                o.y = f2h(fmaxf(acc[m][n][1], 0.f));
                o.z = f2h(fmaxf(acc[m][n][2], 0.f));
                o.w = f2h(fmaxf(acc[m][n][3], 0.f));
                *(ushort4*)&hTp[(((size_t)(b * 2 + hh)) << 17) + ((size_t)d << 10) + nn] = o;
            }
    }

    __syncthreads();
    float* tile = (float*)smem;
#pragma unroll
    for (int m = 0; m < MF; m++)
#pragma unroll
        for (int n = 0; n < NF; n++) {
            const int col = wave * NW + n * 16 + lrow;
#pragma unroll
            for (int q = 0; q < 4; q++)
                tile[(m * 16 + lg * 4 + q) * (N + 8) + col] = acc[m][n][q];
        }
    __syncthreads();
#pragma unroll
    for (int p = 0; p < TM * N / 1024; p++) {
        const int idx = t + p * 256;
        const int row = idx / (N / 4), cg = idx % (N / 4);
        float4 v = *(const float4*)&tile[row * (N + 8) + cg * 4];
        if (RELU) {
            v.x = fmaxf(v.x, 0.f); v.y = fmaxf(v.y, 0.f);
            v.z = fmaxf(v.z, 0.f); v.w = fmaxf(v.w, 0.f);
        }
        const int m = row0 + row;
        if (OUT_MODE == 0) {
            *(float4*)&Yf[(size_t)m * N + cg * 4] = v;
        } else {
            ushort4 hi, lo;
            hi.x = f2bf(v.x); lo.x = f2bf(v.x - bf2f(hi.x));
            hi.y = f2bf(v.y); lo.y = f2bf(v.y - bf2f(hi.y));
            hi.z = f2bf(v.z); lo.z = f2bf(v.z - bf2f(hi.z));
            hi.w = f2bf(v.w); lo.w = f2bf(v.w - bf2f(hi.w));
            if (OUT_MODE == 1 || OUT_MODE == 4) {
                const int b = m >> 10, n = m & 1023;
                const int col = cg * 4;
                const int hh = col >> 7, d = col & 127;
                const size_t addr = (((size_t)(b * 2 + hh) << 10) + n) * DD + d;
                if (OUT_MODE == 1) *(float4*)&Yf[addr] = v;
                *(ushort4*)&O1[addr] = hi;
                *(ushort4*)&O2[addr] = lo;
            } else {
                const size_t addr = (size_t)m * N + cg * 4;
                if (OUT_MODE == 3) *(float4*)&Yf[addr] = v;
                *(ushort4*)&O1[addr] = hi;
                *(ushort4*)&O2[addr] = lo;
            }
        }
    }
}

// ---------------------------------------------------------------------------
// e = sym MFMA (r7 proven: f16 e, upper-tri, coalesced dual write, XCD swz)
// ---------------------------------------------------------------------------
__global__ __launch_bounds__(256) void k_esym_mfma(const ushortT* __restrict__ wHi,
                                                   const ushortT* __restrict__ wLo,
                                                   const ushortT* __restrict__ hHi,
                                                   const ushortT* __restrict__ hLo,
                                                   ushortT* __restrict__ e) {
    __shared__ ushortT smem[20480];
    ushortT* sWjHi = smem;
    ushortT* sWjLo = smem + 2560;
    ushortT* sHjHi = smem + 5120;
    ushortT* sHjLo = smem + 7680;
    ushortT* sWkHi = smem + 10240;
    ushortT* sWkLo = smem + 12800;
    ushortT* sHkHi = smem + 15360;
    ushortT* sHkLo = smem + 17920;

    const int wgid = blockIdx.x;
    const int flat = (wgid & 7) * 272 + (wgid >> 3);
    const int bh = flat / 136;
    int idx = flat % 136, tj = 0;
    while (idx >= 16 - tj) { idx -= 16 - tj; tj++; }
    const int tk = tj + idx;
    const int j0 = tj * 64, k0 = tk * 64;
    const int t = threadIdx.x;
    const int wave = t >> 6, lane = t & 63;
    const int wr = wave >> 1, wc = wave & 1;
    const int lrow = lane & 15, lg = lane >> 4;

    f32x4 acc[2][2];
#pragma unroll
    for (int m = 0; m < 2; m++)
#pragma unroll
        for (int n = 0; n < 2; n++) {
            acc[m][n][0] = 0.f; acc[m][n][1] = 0.f;
            acc[m][n][2] = 0.f; acc[m][n][3] = 0.f;
        }

    const size_t bhbase = (size_t)bh * NN * DD;

    for (int d0 = 0; d0 < DD; d0 += 32) {
        __syncthreads();
        {
            const int row = t >> 2, cu = (t & 3) * 8;
#define STAGE1(SRC, DST, BASE)                                                    \
            *(uint4*)&DST[row * 40 + cu] =                                        \
                *(const uint4*)&SRC[bhbase + (size_t)(BASE + row) * DD + d0 + cu];
            STAGE1(wHi, sWjHi, j0) STAGE1(wLo, sWjLo, j0)
            STAGE1(hHi, sHjHi, j0) STAGE1(hLo, sHjLo, j0)
            STAGE1(wHi, sWkHi, k0) STAGE1(wLo, sWkLo, k0)
            STAGE1(hHi, sHkHi, k0) STAGE1(hLo, sHkLo, k0)
#undef STAGE1
        }
        __syncthreads();

        bf16x8 a0[2], a1[2], b0[2], b1[2];
#pragma unroll
        for (int m = 0; m < 2; m++) {
            const int off = (wr * 32 + m * 16 + lrow) * 40 + lg * 8;
            a0[m] = *(const bf16x8*)&sWjHi[off];
            a1[m] = *(const bf16x8*)&sWjLo[off];
        }
#pragma unroll
        for (int n = 0; n < 2; n++) {
            const int off = (wc * 32 + n * 16 + lrow) * 40 + lg * 8;
            b0[n] = *(const bf16x8*)&sHkHi[off];
            b1[n] = *(const bf16x8*)&sHkLo[off];
        }
#pragma unroll
        for (int m = 0; m < 2; m++)
#pragma unroll
            for (int n = 0; n < 2; n++) {
                acc[m][n] = __builtin_amdgcn_mfma_f32_16x16x32_bf16(a0[m], b0[n], acc[m][n], 0, 0, 0);
                acc[m][n] = __builtin_amdgcn_mfma_f32_16x16x32_bf16(a0[m], b1[n], acc[m][n], 0, 0, 0);
                acc[m][n] = __builtin_amdgcn_mfma_f32_16x16x32_bf16(a1[m], b0[n], acc[m][n], 0, 0, 0);
            }
#pragma unroll
        for (int m = 0; m < 2; m++) {
            const int off = (wr * 32 + m * 16 + lrow) * 40 + lg * 8;
            a0[m] = *(const bf16x8*)&sHjHi[off];
            a1[m] = *(const bf16x8*)&sHjLo[off];
        }
#pragma unroll
        for (int n = 0; n < 2; n++) {
            const int off = (wc * 32 + n * 16 + lrow) * 40 + lg * 8;
            b0[n] = *(const bf16x8*)&sWkHi[off];
            b1[n] = *(const bf16x8*)&sWkLo[off];
        }
#pragma unroll
        for (int m = 0; m < 2; m++)
#pragma unroll
            for (int n = 0; n < 2; n++) {
                acc[m][n] = __builtin_amdgcn_mfma_f32_16x16x32_bf16(a0[m], b0[n], acc[m][n], 0, 0, 0);
                acc[m][n] = __builtin_amdgcn_mfma_f32_16x16x32_bf16(a0[m], b1[n], acc[m][n], 0, 0, 0);
                acc[m][n] = __builtin_amdgcn_mfma_f32_16x16x32_bf16(a1[m], b0[n], acc[m][n], 0, 0, 0);
            }
    }

    __syncthreads();
    ushortT* tileN = smem;
    ushortT* tileT = smem + 4608;
#pragma unroll
    for (int m = 0; m < 2; m++)
#pragma unroll
        for (int n = 0; n < 2; n++) {
            const int jlb = wr * 32 + m * 16 + lg * 4;
            const int kl  = wc * 32 + n * 16 + lrow;
            ushort4 tv;
            tv.x = f2h(acc[m][n][0]); tv.y = f2h(acc[m][n][1]);
            tv.z = f2h(acc[m][n][2]); tv.w = f2h(acc[m][n][3]);
            tileN[(jlb + 0) * 72 + kl] = tv.x;
            tileN[(jlb + 1) * 72 + kl] = tv.y;
            tileN[(jlb + 2) * 72 + kl] = tv.z;
            tileN[(jlb + 3) * 72 + kl] = tv.w;
            *(ushort4*)&tileT[kl * 72 + jlb] = tv;
        }
    __syncthreads();
#pragma unroll
    for (int it = 0; it < 4; it++) {
        const int i2 = t + it * 256;
        const int row = i2 >> 4, ch = (i2 & 15) * 4;
        *(uint2*)&e[((size_t)bh * NN + j0 + row) * NN + k0 + ch] =
            *(const uint2*)&tileN[row * 72 + ch];
        if (tj != tk)
            *(uint2*)&e[((size_t)bh * NN + k0 + row) * NN + j0 + ch] =
                *(const uint2*)&tileT[row * 72 + ch];
    }
}

// ---------------------------------------------------------------------------
__global__ __launch_bounds__(256) void k_buildT(const float* __restrict__ adj,
                                                u64* __restrict__ bits) {
    const int gid = blockIdx.x * 256 + threadIdx.x;
    const int k  = gid & 1023;
    const int tw = (gid >> 10) & 15;
    const int b  = gid >> 14;
    const float* ac = adj + ((size_t)b << 20) + k;
    u64 w = 0;
#pragma unroll 8
    for (int jj = 0; jj < 64; jj++) {
        if (ac[(size_t)(tw * 64 + jj) << 10] != 0.f) w |= 1ull << jj;
    }
    bits[((size_t)((b << 10) | k)) * 16 + tw] = w;
}

__global__ __launch_bounds__(256) void k_cnt(const u64* __restrict__ bits,
                                             int* __restrict__ ccnt) {
    const int gid = blockIdx.x * 256 + threadIdx.x;
    const u64* wb = bits + (size_t)gid * 16;
    int c = 0;
#pragma unroll
    for (int tw = 0; tw < 16; tw++) c += __popcll(wb[tw]);
    ccnt[gid] = c;
}

// ---------------------------------------------------------------------------
__global__ __launch_bounds__(256) void k_smA(const ushortT* __restrict__ e,
                                             const u64* __restrict__ bits,
                                             float* __restrict__ pm,
                                             float* __restrict__ ps) {
    const int gid = blockIdx.x * 256 + threadIdx.x;
    const int kg = gid & 255;
    const int jc = (gid >> 8) & 63;
    const int bh = gid >> 14;
    const int b  = bh >> 1;
    const int k4 = kg * 4;
    const int tw = jc >> 2;
    const int bo = (jc & 3) * 16;
    u64 w[4];
#pragma unroll
    for (int i = 0; i < 4; i++)
        w[i] = bits[((size_t)((b << 10) | (k4 + i))) * 16 + tw];
    const ushortT* ec = e + ((size_t)bh << 20) + (size_t)(jc * 16) * NN + k4;
    float m[4] = {0.f, 0.f, 0.f, 0.f};
    float s[4] = {0.f, 0.f, 0.f, 0.f};
#pragma unroll
    for (int r = 0; r < 16; r++) {
        const ushort4 ev = *(const ushort4*)&ec[(size_t)r * NN];
        const float evs[4] = {h2f(ev.x), h2f(ev.y), h2f(ev.z), h2f(ev.w)};
#pragma unroll
        for (int i = 0; i < 4; i++) {
            const bool on = (w[i] >> (bo + r)) & 1;
            const float v = on ? evs[i] : 0.f;
            const float mn = fmaxf(m[i], v);
            s[i] = s[i] * __expf(m[i] - mn) + (on ? __expf(v - mn) : 0.f);
            m[i] = mn;
        }
    }
    const size_t o = (((size_t)bh * 64 + jc) << 10) + k4;
    *(float4*)&pm[o] = make_float4(m[0], m[1], m[2], m[3]);
    *(float4*)&ps[o] = make_float4(s[0], s[1], s[2], s[3]);
}

__global__ __launch_bounds__(256) void k_smB(const float* __restrict__ pm,
                                             const float* __restrict__ ps,
                                             const int* __restrict__ ccnt,
                                             float* __restrict__ smax,
                                             float* __restrict__ sdinv) {
    __shared__ float lm[4][64], ls[4][64];
    const int t = threadIdx.x, q = t >> 6, lane = t & 63;
    const int colg = blockIdx.x * 64 + lane;
    const int bh = colg >> 10, k = colg & 1023;
    const int b  = bh >> 1;
    float M = 0.f, S = 0.f;
#pragma unroll 4
    for (int i = 0; i < 16; i++) {
        const int jc = q * 16 + i;
        const size_t o = (((size_t)bh * 64 + jc) << 10) + k;
        const float pmv = pm[o], psv = ps[o];
        const float mn = fmaxf(M, pmv);
        S = S * __expf(M - mn) + psv * __expf(pmv - mn);
        M = mn;
    }
    lm[q][lane] = M; ls[q][lane] = S;
    __syncthreads();
    if (q == 0) {
#pragma unroll
        for (int qq = 1; qq < 4; qq++) {
            const float pmv = lm[qq][lane], psv = ls[qq][lane];
            const float mn = fmaxf(M, pmv);
            S = S * __expf(M - mn) + psv * __expf(pmv - mn);
            M = mn;
        }
        S += (float)(NN - ccnt[(b << 10) + k]) * __expf(-M);
        smax[colg] = M;
        sdinv[colg] = 1.f / S;
    }
}

__global__ __launch_bounds__(256) void k_smC(const ushortT* __restrict__ e,
                                             const u64* __restrict__ bits,
                                             const float* __restrict__ smax,
                                             const float* __restrict__ sdinv,
                                             ushortT* __restrict__ att) {
    const int gid = blockIdx.x * 256 + threadIdx.x;
    const int kg = gid & 255;
    const int jc = (gid >> 8) & 63;
    const int bh = gid >> 14;
    const int b  = bh >> 1;
    const int k4 = kg * 4;
    const int tw = jc >> 2;
    const int bo = (jc & 3) * 16;
    u64 w[4];
#pragma unroll
    for (int i = 0; i < 4; i++)
        w[i] = bits[((size_t)((b << 10) | (k4 + i))) * 16 + tw];
    const float4 m4 = *(const float4*)&smax[(bh << 10) + k4];
    const float4 d4 = *(const float4*)&sdinv[(bh << 10) + k4];
    const float ms[4] = {m4.x, m4.y, m4.z, m4.w};
    const float ds[4] = {d4.x, d4.y, d4.z, d4.w};
    const ushortT* ec = e + ((size_t)bh << 20) + (size_t)(jc * 16) * NN + k4;
    ushortT* ac = att + ((size_t)bh << 20) + (size_t)(jc * 16) * NN + k4;
#pragma unroll
    for (int r = 0; r < 16; r++) {
        const ushort4 ev = *(const ushort4*)&ec[(size_t)r * NN];
        const float evs[4] = {h2f(ev.x), h2f(ev.y), h2f(ev.z), h2f(ev.w)};
        ushort4 o;
        ushortT os[4];
#pragma unroll
        for (int i = 0; i < 4; i++) {
            const bool on = (w[i] >> (bo + r)) & 1;
            os[i] = f2h(on ? __expf(evs[i] - ms[i]) * ds[i] : 0.f);
        }
        o.x = os[0]; o.y = os[1]; o.z = os[2]; o.w = os[3];
        *(ushort4*)&ac[(size_t)r * NN] = o;
    }
}

// ---------------------------------------------------------------------------
// Dense f16 MFMA hop, 8 waves, j-chunk 128, XCD swizzle.
// MODE 0: zin = hT; beta computed in-block, writes mixed z1.
// MODE 1: zin = previous mixed z; beta from global.
// SPLIT:  write relu+bf16-split z [bh][n][d] via LDS retile (fuses old k_fin);
//         no zT output.
// ---------------------------------------------------------------------------
template<int MODE, bool SPLIT>
__global__ __launch_bounds__(512) void k_hop(const ushortT* __restrict__ att,
                                             const ushortT* __restrict__ zin,
                                             const ushortT* __restrict__ hT,
                                             float* __restrict__ beta,
                                             const float* __restrict__ Wbw,
                                             const float* __restrict__ Wbb,
                                             ushortT* __restrict__ zout,
                                             ushortT* __restrict__ zHi,
                                             ushortT* __restrict__ zLo) {
    __shared__ ushortT smem[64 * 136 + 128 * 136];
    ushortT* sA = smem;                         // [64][136]
    ushortT* sB = smem + 64 * 136;              // [128][136]
    const int bid = blockIdx.x;                 // 256 = 8 XCD x 32
    const int flat = (bid & 7) * 32 + (bid >> 3);
    const int bh = flat >> 4;
    const int i0 = (flat & 15) * 64;
    const int t = threadIdx.x, wave = t >> 6, lane = t & 63;
    const int wr = wave >> 2, wc = wave & 3;
    const int lrow = lane & 15, lg = lane >> 4;
    const ushortT* attb = att + ((size_t)bh << 20);
    const ushortT* hTb  = hT + (size_t)bh * 131072;
    const ushortT* zb   = (MODE == 0) ? hTb : zin + (size_t)bh * 131072;

    f32x4 acc[2][2];
#pragma unroll
    for (int m = 0; m < 2; m++)
#pragma unroll
        for (int n = 0; n < 2; n++) {
            acc[m][n][0]=0.f; acc[m][n][1]=0.f; acc[m][n][2]=0.f; acc[m][n][3]=0.f;
        }

    for (int j0 = 0; j0 < NN; j0 += 128) {
        __syncthreads();
#pragma unroll
        for (int q = 0; q < 2; q++) {
            const int u = t + q * 512;
            const int row = u >> 4, c8 = (u & 15) * 8;
            *(uint4*)&sA[row * 136 + c8] =
                *(const uint4*)&attb[(size_t)(i0 + row) * NN + j0 + c8];
        }
#pragma unroll
        for (int q = 0; q < 4; q++) {
            const int u = t + q * 512;
            const int row = u >> 4, c8 = (u & 15) * 8;
            *(uint4*)&sB[row * 136 + c8] =
                *(const uint4*)&zb[(size_t)row * NN + j0 + c8];
        }
        __syncthreads();
#pragma unroll
        for (int ks = 0; ks < 4; ks++) {
            f16x8 a[2], b[2];
#pragma unroll
            for (int m = 0; m < 2; m++)
                a[m] = *(const f16x8*)&sA[(wr * 32 + m * 16 + lrow) * 136 + ks * 32 + lg * 8];
#pragma unroll
            for (int n = 0; n < 2; n++)
                b[n] = *(const f16x8*)&sB[(wc * 32 + n * 16 + lrow) * 136 + ks * 32 + lg * 8];
#pragma unroll
            for (int m = 0; m < 2; m++)
#pragma unroll
                for (int n = 0; n < 2; n++)
                    acc[m][n] = __builtin_amdgcn_mfma_f32_16x16x32_f16(a[m], b[n], acc[m][n], 0, 0, 0);
        }
    }

    ushortT* zo = zout + (size_t)bh * 131072;
    ushortT* ztile = nullptr;   // [64 n][136 d] for SPLIT retile

    if (MODE == 1) {
        const float* betab = beta + ((size_t)bh << 10);
        if (SPLIT) { __syncthreads(); ztile = smem; }   // sA region dead
#pragma unroll
        for (int m = 0; m < 2; m++)
#pragma unroll
            for (int n = 0; n < 2; n++) {
                const int d = wc * 32 + n * 16 + lrow;
                const int i = i0 + wr * 32 + m * 16 + lg * 4;
                const float4 bev = *(const float4*)&betab[i];
                const ushort4 hv = *(const ushort4*)&hTb[(size_t)d * NN + i];
                ushort4 o;
                o.x = f2h(bev.x * h2f(hv.x) + (1.f - bev.x) * fmaxf(acc[m][n][0], 0.f));
                o.y = f2h(bev.y * h2f(hv.y) + (1.f - bev.y) * fmaxf(acc[m][n][1], 0.f));
                o.z = f2h(bev.z * h2f(hv.z) + (1.f - bev.z) * fmaxf(acc[m][n][2], 0.f));
                o.w = f2h(bev.w * h2f(hv.w) + (1.f - bev.w) * fmaxf(acc[m][n][3], 0.f));
                if (SPLIT) {
                    const int il = wr * 32 + m * 16 + lg * 4;
                    ztile[(il + 0) * 136 + d] = o.x;
                    ztile[(il + 1) * 136 + d] = o.y;
                    ztile[(il + 2) * 136 + d] = o.z;
                    ztile[(il + 3) * 136 + d] = o.w;
                } else {
                    *(ushort4*)&zo[(size_t)d * NN + i] = o;
                }
            }
    } else {
        // ---- MODE 0: beta in-block, then mixed z1 ----
        ushort4 ofrag[2][2];
#pragma unroll
        for (int m = 0; m < 2; m++)
#pragma unroll
            for (int n = 0; n < 2; n++) {
                ushort4 o;
                o.x = f2h(fmaxf(acc[m][n][0], 0.f));
                o.y = f2h(fmaxf(acc[m][n][1], 0.f));
                o.z = f2h(fmaxf(acc[m][n][2], 0.f));
                o.w = f2h(fmaxf(acc[m][n][3], 0.f));
                ofrag[m][n] = o;
            }
        __syncthreads();                        // staging LDS dead; reuse
        ushortT* azl = smem;                    // [128][72]
        ushortT* hl  = smem + 128 * 72;         // [128][72]
        float*   bl  = (float*)(smem + 2 * 128 * 72);  // [64]
#pragma unroll
        for (int m = 0; m < 2; m++)
#pragma unroll
            for (int n = 0; n < 2; n++) {
                const int d = wc * 32 + n * 16 + lrow;
                const int il = wr * 32 + m * 16 + lg * 4;
                const ushort4 o = ofrag[m][n];
                azl[d * 72 + il + 0] = o.x;
                azl[d * 72 + il + 1] = o.y;
                azl[d * 72 + il + 2] = o.z;
                azl[d * 72 + il + 3] = o.w;
            }
#pragma unroll
        for (int q = 0; q < 2; q++) {           // hl: 128 rows x 64 cols
            const int u = t + q * 512;
            const int row = u >> 3, c8 = (u & 7) * 8;
            *(uint4*)&hl[row * 72 + c8] =
                *(const uint4*)&hTb[(size_t)row * NN + i0 + c8];
        }
        __syncthreads();
        {
            const int i = t >> 3, c = t & 7;
            float p = 0.f;
#pragma unroll
            for (int dd = 0; dd < 16; dd++) {
                const int d = c * 16 + dd;
                p += h2f(hl[d * 72 + i]) * Wbw[d] + h2f(azl[d * 72 + i]) * Wbw[DD + d];
            }
            p += __shfl_down(p, 4, 8);
            p += __shfl_down(p, 2, 8);
            p += __shfl_down(p, 1, 8);
            if (c == 0) {
                const float be = 1.f / (1.f + expf(-(p + Wbb[0])));
                beta[(bh << 10) + i0 + i] = be;
                bl[i] = be;
            }
        }
        __syncthreads();                        // azl dead after beta dot
        if (SPLIT) ztile = smem;                // reuse azl region (8704<=9216)
#pragma unroll
        for (int m = 0; m < 2; m++)
#pragma unroll
            for (int n = 0; n < 2; n++) {
                const int d = wc * 32 + n * 16 + lrow;
                const int il = wr * 32 + m * 16 + lg * 4;
                const ushort4 az = ofrag[m][n];
                ushort4 o;
                o.x = f2h(bl[il+0] * h2f(hl[d*72+il+0]) + (1.f - bl[il+0]) * h2f(az.x));
                o.y = f2h(bl[il+1] * h2f(hl[d*72+il+1]) + (1.f - bl[il+1]) * h2f(az.y));
                o.z = f2h(bl[il+2] * h2f(hl[d*72+il+2]) + (1.f - bl[il+2]) * h2f(az.z));
                o.w = f2h(bl[il+3] * h2f(hl[d*72+il+3]) + (1.f - bl[il+3]) * h2f(az.w));
                if (SPLIT) {
                    ztile[(il + 0) * 136 + d] = o.x;
                    ztile[(il + 1) * 136 + d] = o.y;
                    ztile[(il + 2) * 136 + d] = o.z;
                    ztile[(il + 3) * 136 + d] = o.w;
                } else {
                    *(ushort4*)&zo[(size_t)d * NN + i0 + il] = o;
                }
            }
    }

    if (SPLIT) {
        __syncthreads();
        const size_t obase = (size_t)bh * 131072 + (size_t)i0 * DD;
#pragma unroll
        for (int p = 0; p < 2; p++) {
            const int idx = t + p * 512;
            const int row = idx >> 4, dq = (idx & 15) * 8;
            ushortT zv[8], hi8[8], lo8[8];
            *(uint4*)zv = *(const uint4*)&ztile[row * 136 + dq];
#pragma unroll
            for (int i = 0; i < 8; i++) {
                const float v = fmaxf(h2f(zv[i]), 0.f);
                hi8[i] = f2bf(v);
                lo8[i] = f2bf(v - bf2f(hi8[i]));
            }
            *(uint4*)&zHi[obase + (size_t)row * DD + dq] = *(uint4*)hi8;
            *(uint4*)&zLo[obase + (size_t)row * DD + dq] = *(uint4*)lo8;
        }
    }
}

// c = c2 - c1 fp32 + bf16 hi/lo split
__global__ __launch_bounds__(256) void k_sub(const float* __restrict__ c2,
                                             const float* __restrict__ c1,
                                             float* __restrict__ c,
                                             ushortT* __restrict__ cHi,
                                             ushortT* __restrict__ cLo) {
    const int g = blockIdx.x * 256 + threadIdx.x;
    const float4 a = ((const float4*)c2)[g];
    const float4 b = ((const float4*)c1)[g];
    const float4 v = make_float4(a.x - b.x, a.y - b.y, a.z - b.z, a.w - b.w);
    ((float4*)c)[g] = v;
    ushort4 hi, lo;
    hi.x = f2bf(v.x); lo.x = f2bf(v.x - bf2f(hi.x));
    hi.y = f2bf(v.y); lo.y = f2bf(v.y - bf2f(hi.y));
    hi.z = f2bf(v.z); lo.z = f2bf(v.z - bf2f(hi.z));
    hi.w = f2bf(v.w); lo.w = f2bf(v.w - bf2f(hi.w));
    ((ushort4*)cHi)[g] = hi;
    ((ushort4*)cLo)[g] = lo;
}

__global__ __launch_bounds__(128) void k_poolA(const float* __restrict__ c,
                                               const float* __restrict__ valid,
                                               float* __restrict__ pp,
                                               float* __restrict__ pv) {
    const int bc = blockIdx.x;
    const int b = bc >> 4, ch = bc & 15;
    const int d = threadIdx.x;
    const float* cb = c + ((size_t)b << 17) + (size_t)(ch * 64) * DD;
    const float* vb = valid + (b << 10) + ch * 64;
    float s = 0.f, sv = 0.f;
#pragma unroll 8
    for (int i = 0; i < 64; i++) { const float v = vb[i]; s += cb[(size_t)i * DD + d] * v; sv += v; }
    pp[bc * 128 + d] = s;
    if (d == 0) pv[bc] = sv;
}

__global__ __launch_bounds__(256) void k_poolB(const float* __restrict__ pp,
                                               const float* __restrict__ pv,
                                               float* __restrict__ pooled) {
    const int gid = blockIdx.x * 256 + threadIdx.x;
    const int b = gid >> 7, d = gid & 127;
    float s = 0.f, sv = 0.f;
#pragma unroll
    for (int ch = 0; ch < 16; ch++) {
        s  += pp[(b * 16 + ch) * 128 + d];
        sv += pv[b * 16 + ch];
    }
    pooled[b * 128 + d] = s / sv;
}

template<int K, int NOUT, bool RELU>
__global__ void k_fc(const float* __restrict__ X, const float* __restrict__ W,
                     const float* __restrict__ bias, float* __restrict__ Y) {
    const int gid = blockIdx.x * blockDim.x + threadIdx.x;
    if (gid >= BB * NOUT) return;
    const int b = gid / NOUT, o = gid % NOUT;
    float s = bias[o];
    for (int i = 0; i < K; i++) s += X[(size_t)b * K + i] * W[(size_t)i * NOUT + o];
    Y[gid] = RELU ? fmaxf(s, 0.f) : s;
}

__global__ void k_fc2(const float* __restrict__ X, const float* __restrict__ W,
                      const float* __restrict__ bias, float* __restrict__ out) {
    const int b = threadIdx.x >> 6, lane = threadIdx.x & 63;
    float s = 0.f;
    for (int i = lane; i < DFCN; i += 64) s += X[(size_t)b * DFCN + i] * W[i];
#pragma unroll
    for (int off = 32; off > 0; off >>= 1) s += __shfl_down(s, off);
    if (lane == 0) out[b] = 1.f / (1.f + expf(-(s + bias[0])));
}

// ---------------------------------------------------------------------------
extern "C" void kernel_launch(void* const* d_in, const int* in_sizes, int n_in,
                              void* d_out, int out_size, void* d_ws, size_t ws_size,
                              hipStream_t stream) {
    const float* x        = (const float*)d_in[0];
    const float* adj1     = (const float*)d_in[1];
    const float* adj2     = (const float*)d_in[2];
    const float* valid    = (const float*)d_in[3];
    const float* embede_w = (const float*)d_in[4];
    const float* Wh       = (const float*)d_in[5];
    const float* We       = (const float*)d_in[6];
    const float* Wbw      = (const float*)d_in[7];
    const float* Wbb      = (const float*)d_in[8];
    const float* Wo       = (const float*)d_in[9];
    const float* fc0_w    = (const float*)d_in[10];
    const float* fc0_b    = (const float*)d_in[11];
    const float* fc1_w    = (const float*)d_in[12];
    const float* fc1_b    = (const float*)d_in[13];
    const float* fc2_w    = (const float*)d_in[14];
    const float* fc2_b    = (const float*)d_in[15];

    // ---- workspace carve ----
    float* ws = (float*)d_ws;
    float* c      = ws;                          // 1,048,576 f
    float* c1     = c      + (size_t)1048576;    // 1,048,576 f
    float* c2     = c1     + (size_t)1048576;    // 1,048,576 f
    float* beta   = c2     + (size_t)1048576;    // 16,384 f
    float* pm     = beta   + (size_t)16384;      // 1,048,576 f
    float* ps     = pm     + (size_t)1048576;    // 1,048,576 f
    float* smax   = ps     + (size_t)1048576;    // 16,384 f
    float* sdinv  = smax   + (size_t)16384;      // 16,384 f
    float* pp     = sdinv  + (size_t)16384;      // 16,384 f
    float* pv     = pp     + (size_t)16384;      // 128 f
    float* pooled = pv     + (size_t)128;        // 1,024 f
    float* f0     = pooled + (size_t)1024;       // 4,096 f
    float* f1     = f0     + (size_t)4096;       // 4,096 f
    ushortT* hHi  = (ushortT*)(f1 + 4096);       // 2,097,152 us each
    ushortT* hLo  = hHi + (size_t)2097152;
    ushortT* wHi  = hLo + (size_t)2097152;
    ushortT* wLo  = wHi + (size_t)2097152;
    ushortT* hT   = wLo + (size_t)2097152;
    ushortT* zTa  = hT  + (size_t)2097152;
    ushortT* zTb  = zTa + (size_t)2097152;
    ushortT* cHi  = zTb + (size_t)2097152;       // 1,048,576 us each
    ushortT* cLo  = cHi + (size_t)1048576;
    ushortT* zHi  = cLo + (size_t)1048576;       // 2,097,152 us each
    ushortT* zLo  = zHi + (size_t)2097152;
    ushortT* att  = zLo + (size_t)2097152;       // 16,777,216 us
    ushortT* e    = att + (size_t)16777216;      // 16,777,216 us
    ushortT* WhTh = e   + (size_t)16777216;      // 131,072 us each
    ushortT* WhTl = WhTh + (size_t)131072;
    ushortT* WeTh = WhTl + (size_t)131072;       // 65,536 each
    ushortT* WeTl = WeTh + (size_t)65536;
    ushortT* WoTh = WeTl + (size_t)65536;        // 131,072 each
    ushortT* WoTl = WoTh + (size_t)131072;
    ushortT* EmTh = WoTl + (size_t)131072;       // 16,384 each
    ushortT* EmTl = EmTh + (size_t)16384;
    u64* bits1    = (u64*)(EmTl + (size_t)16384);
    u64* bits2    = bits1 + (size_t)131072;
    int* ccnt1    = (int*)(bits2 + (size_t)131072);
    int* ccnt2    = ccnt1 + 8192;

    // ---- one-time per launch: masks + weight splits ----
    k_buildT<<<512, 256, 0, stream>>>(adj1, bits1);
    k_buildT<<<512, 256, 0, stream>>>(adj2, bits2);
    k_cnt<<<32, 256, 0, stream>>>(bits1, ccnt1);
    k_cnt<<<32, 256, 0, stream>>>(bits2, ccnt2);
    k_splitWT<128,256><<<dim3(8,4,4), 256, 0, stream>>>(Wh, WhTh, WhTl);
    k_splitWT<128,128><<<dim3(4,4,4), 256, 0, stream>>>(We, WeTh, WeTl);
    k_splitWT<256,128><<<dim3(4,8,4), 256, 0, stream>>>(Wo, WoTh, WoTl);
    k_splitWT<128,128><<<dim3(4,4,1), 256, 0, stream>>>(embede_w, EmTh, EmTl);

    // c = x @ embede_w
    k_mgemm<128,128,32,false,2,3><<<256, 256, 0, stream>>>(
        nullptr, nullptr, x, EmTh, EmTl, c, cHi, cLo);

    for (int k = 0; k < LL; k++) {
        const int nhop = k + 1;
        const float* Wbw_k = Wbw + (size_t)k * 256;
        const float* Wbb_k = Wbb + k;
        // h = relu(c @ Wh[k]) -> splits [bh][n][d] + hT f16 [bh][d][n] (fused trT)
        k_mgemm<128,256,32,true,0,4><<<256, 256, 0, stream>>>(
            cHi, cLo, nullptr, WhTh + (size_t)k*32768, WhTl + (size_t)k*32768,
            (float*)hT, hHi, hLo);
        // hW = h @ We[k] -> splits row-major
        k_mgemm<128,128,64,false,0,2><<<256, 256, 0, stream>>>(
            hHi, hLo, nullptr, WeTh + (size_t)k*16384, WeTl + (size_t)k*16384, nullptr, wHi, wLo);
        k_esym_mfma<<<2176, 256, 0, stream>>>(wHi, wLo, hHi, hLo, e);

        for (int br = 0; br < 2; br++) {
            const u64* bits = (br == 0) ? bits1 : bits2;
            const int* ccnt = (br == 0) ? ccnt1 : ccnt2;
            float*     cb   = (br == 0) ? c1    : c2;

            k_smA<<<1024, 256, 0, stream>>>(e, bits, pm, ps);
            k_smB<<<256, 256, 0, stream>>>(pm, ps, ccnt, smax, sdinv);
            k_smC<<<1024, 256, 0, stream>>>(e, bits, smax, sdinv, att);

            if (nhop == 1) {
                // single hop: beta in-block + direct split output (fused fin)
                k_hop<0,true><<<256, 512, 0, stream>>>(
                    att, nullptr, hT, beta, Wbw_k, Wbb_k, nullptr, zHi, zLo);
            } else {
                k_hop<0,false><<<256, 512, 0, stream>>>(
                    att, nullptr, hT, beta, Wbw_k, Wbb_k, zTb, nullptr, nullptr);
                ushortT* zA = zTb; ushortT* zB = zTa;
                for (int tpp = 1; tpp < nhop; tpp++) {
                    if (tpp == nhop - 1) {
                        k_hop<1,true><<<256, 512, 0, stream>>>(
                            att, zA, hT, beta, nullptr, nullptr, nullptr, zHi, zLo);
                    } else {
                        k_hop<1,false><<<256, 512, 0, stream>>>(
                            att, zA, hT, beta, nullptr, nullptr, zB, nullptr, nullptr);
                        ushortT* tmp = zA; zA = zB; zB = tmp;
                    }
                }
            }
            // cb = relu(z) @ Wo[k]
            k_mgemm<256,128,32,false,1,0><<<256, 256, 0, stream>>>(
                zHi, zLo, nullptr, WoTh + (size_t)k*32768, WoTl + (size_t)k*32768, cb, nullptr, nullptr);
        }
        k_sub<<<1024, 256, 0, stream>>>(c2, c1, c, cHi, cLo);
    }

    k_poolA<<<128, 128, 0, stream>>>(c, valid, pp, pv);
    k_poolB<<<4, 256, 0, stream>>>(pp, pv, pooled);
    k_fc<128, DFCN, true><<<16, 256, 0, stream>>>(pooled, fc0_w, fc0_b, f0);
    k_fc<DFCN, DFCN, true><<<16, 256, 0, stream>>>(f0, fc1_w, fc1_b, f1);
    k_fc2<<<1, 512, 0, stream>>>(f1, fc2_w, fc2_b, (float*)d_out);
}

// Round 12
// 823.775 us; speedup vs baseline: 1.4882x; 1.2813x over previous
//
#include <hip/hip_runtime.h>
#include <math.h>

#define BB 8
#define NN 1024
#define DD 128
#define HH 2
#define LL 4
#define DFCN 512

// per-branch buffer strides (elements)
#define ATT_S 16777216u
#define PM_S  1048576u
#define SM_S  16384u
#define Z_S   2097152u
#define BITS_S 131072u
#define CCNT_S 8192u
#define C_S   1048576u

typedef __attribute__((ext_vector_type(8))) short bf16x8;
typedef __attribute__((ext_vector_type(8))) _Float16 f16x8;
typedef __attribute__((ext_vector_type(4))) float f32x4;
typedef unsigned long long u64;
typedef unsigned short ushortT;

static __device__ __forceinline__ unsigned short f2bf(float f) {
    unsigned u = __float_as_uint(f);
    u += 0x7FFF + ((u >> 16) & 1);
    return (unsigned short)(u >> 16);
}
static __device__ __forceinline__ float bf2f(unsigned short s) {
    return __uint_as_float(((unsigned)s) << 16);
}
static __device__ __forceinline__ unsigned short f2h(float f) {
    _Float16 h = (_Float16)f; return *(unsigned short*)&h;
}
static __device__ __forceinline__ float h2f(unsigned short u) {
    _Float16 h; *(unsigned short*)&h = u; return (float)h;
}

// ---------------------------------------------------------------------------
// Weight pre-split: W[l][k][n] fp32 -> WT hi/lo [l][n][k] bf16 (32x32 tiles)
// ---------------------------------------------------------------------------
template<int K, int N>
__global__ __launch_bounds__(256) void k_splitWT(const float* __restrict__ W,
                                                 ushortT* __restrict__ Thi,
                                                 ushortT* __restrict__ Tlo) {
    __shared__ float tile[32][33];
    const int l = blockIdx.z;
    const int n0 = blockIdx.x * 32, k0 = blockIdx.y * 32;
    const float* Wl = W + (size_t)l * K * N;
    ushortT* Hl = Thi + (size_t)l * K * N;
    ushortT* Ll = Tlo + (size_t)l * K * N;
    const int t = threadIdx.x;
    const int r = t >> 5, cc = t & 31;
#pragma unroll
    for (int q = 0; q < 4; q++)
        tile[r + q * 8][cc] = Wl[(size_t)(k0 + r + q * 8) * N + n0 + cc];
    __syncthreads();
#pragma unroll
    for (int q = 0; q < 4; q++) {
        const int nl = r + q * 8, kl = cc;
        const float v = tile[kl][nl];
        const ushortT hi = f2bf(v);
        Hl[(size_t)(n0 + nl) * K + k0 + kl] = hi;
        Ll[(size_t)(n0 + nl) * K + k0 + kl] = f2bf(v - bf2f(hi));
    }
}

// ---------------------------------------------------------------------------
// Unified split-bf16 MFMA GEMM. gridDim.y = branch (brA/brY element strides).
// OUT_MODE 0: Yf fp32 row-major
//          1: scatter [bh][n][d] fp32 + splits
//          2: splits row-major only
//          3: Yf fp32 + splits row-major
//          4: scatter splits [bh][n][d] + hT f16 [bh][d][n] (Yf reused as hT)
// ---------------------------------------------------------------------------
template<int K, int N, int TM, bool RELU, int IN_MODE, int OUT_MODE>
__global__ __launch_bounds__(256) void k_mgemm(const ushortT* __restrict__ Ahi,
                                               const ushortT* __restrict__ Alo,
                                               const float* __restrict__ Afp,
                                               const ushortT* __restrict__ BThi,
                                               const ushortT* __restrict__ BTlo,
                                               float* __restrict__ Yf,
                                               ushortT* __restrict__ O1,
                                               ushortT* __restrict__ O2,
                                               int brA, int brY) {
    constexpr int MF = TM / 16;
    constexpr int NW = N / 4;
    constexpr int NF = NW / 16;
    constexpr int SSTG = (TM + N) * 160;
    constexpr int SEPI = TM * (N + 8) * 4;
    constexpr int SMEM = SSTG > SEPI ? SSTG : SEPI;
    __shared__ char smem[SMEM];
    ushortT* sAhi = (ushortT*)smem;
    ushortT* sAlo = sAhi + TM * 40;
    ushortT* sBhi = sAlo + TM * 40;
    ushortT* sBlo = sBhi + (size_t)N * 40;
    const int t = threadIdx.x;
    const int wave = t >> 6, lane = t & 63;
    const int lrow = lane & 15, lg = lane >> 4;
    const int row0 = blockIdx.x * TM;
    const int br = blockIdx.y;
    if (Ahi) { Ahi += (size_t)br * brA; Alo += (size_t)br * brA; }
    if (Yf && OUT_MODE == 0) Yf += (size_t)br * brY;

    f32x4 acc[MF][NF];
#pragma unroll
    for (int m = 0; m < MF; m++)
#pragma unroll
        for (int n = 0; n < NF; n++) {
            acc[m][n][0]=0.f; acc[m][n][1]=0.f; acc[m][n][2]=0.f; acc[m][n][3]=0.f;
        }

    for (int k0 = 0; k0 < K; k0 += 32) {
        __syncthreads();
        if (IN_MODE == 2) {
#pragma unroll
            for (int p = 0; p < TM * 8 / 256; p++) {
                const int idx = t + p * 256;
                const int row = idx >> 3, cu = (idx & 7) * 4;
                const float4 v = *(const float4*)&Afp[(size_t)(row0 + row) * K + k0 + cu];
                ushort4 hi, lo;
                hi.x = f2bf(v.x); lo.x = f2bf(v.x - bf2f(hi.x));
                hi.y = f2bf(v.y); lo.y = f2bf(v.y - bf2f(hi.y));
                hi.z = f2bf(v.z); lo.z = f2bf(v.z - bf2f(hi.z));
                hi.w = f2bf(v.w); lo.w = f2bf(v.w - bf2f(hi.w));
                *(ushort4*)&sAhi[row * 40 + cu] = hi;
                *(ushort4*)&sAlo[row * 40 + cu] = lo;
            }
        } else {
#pragma unroll
            for (int p = 0; p < TM * 8 / 256; p++) {
                const int idx = t + p * 256;
                const bool ishi = idx < TM * 4;
                const int i2 = ishi ? idx : idx - TM * 4;
                const int row = i2 >> 2, cu = (i2 & 3) * 8;
                size_t ga;
                if (IN_MODE == 0) {
                    ga = (size_t)(row0 + row) * K + k0 + cu;
                } else {
                    const int m = row0 + row;
                    const int b = m >> 10, n = m & 1023;
                    const int hh = k0 >> 7, d = (k0 & 127) + cu;
                    ga = (((size_t)(b * 2 + hh) << 10) + n) * DD + d;
                }
                const ushortT* src = ishi ? Ahi : Alo;
                ushortT* dst = ishi ? sAhi : sAlo;
                *(uint4*)&dst[row * 40 + cu] = *(const uint4*)&src[ga];
            }
        }
#pragma unroll
        for (int p = 0; p < N / 32; p++) {
            const int idx = t + p * 256;
            const bool ishi = idx < N * 4;
            const int i2 = ishi ? idx : idx - N * 4;
            const int row = i2 >> 2, cu = (i2 & 3) * 8;
            const ushortT* src = ishi ? BThi : BTlo;
            ushortT* dst = ishi ? sBhi : sBlo;
            *(uint4*)&dst[row * 40 + cu] = *(const uint4*)&src[(size_t)row * K + k0 + cu];
        }
        __syncthreads();
        bf16x8 a0[MF], a1[MF], b0[NF], b1[NF];
#pragma unroll
        for (int m = 0; m < MF; m++) {
            const int off = (m * 16 + lrow) * 40 + lg * 8;
            a0[m] = *(const bf16x8*)&sAhi[off];
            a1[m] = *(const bf16x8*)&sAlo[off];
        }
#pragma unroll
        for (int n = 0; n < NF; n++) {
            const int off = (wave * NW + n * 16 + lrow) * 40 + lg * 8;
            b0[n] = *(const bf16x8*)&sBhi[off];
            b1[n] = *(const bf16x8*)&sBlo[off];
        }
#pragma unroll
        for (int m = 0; m < MF; m++)
#pragma unroll
            for (int n = 0; n < NF; n++) {
                acc[m][n] = __builtin_amdgcn_mfma_f32_16x16x32_bf16(a0[m], b0[n], acc[m][n], 0, 0, 0);
                acc[m][n] = __builtin_amdgcn_mfma_f32_16x16x32_bf16(a0[m], b1[n], acc[m][n], 0, 0, 0);
                acc[m][n] = __builtin_amdgcn_mfma_f32_16x16x32_bf16(a1[m], b0[n], acc[m][n], 0, 0, 0);
            }
    }

    if (OUT_MODE == 4) {
        ushortT* hTp = (ushortT*)Yf;
        const int b = row0 >> 10;
        const int nb = row0 & 1023;
#pragma unroll
        for (int m = 0; m < MF; m++)
#pragma unroll
            for (int n = 0; n < NF; n++) {
                const int col = wave * NW + n * 16 + lrow;
                const int hh = col >> 7, d = col & 127;
                const int nn = nb + m * 16 + lg * 4;
                ushort4 o;
                o.x = f2h(fmaxf(acc[m][n][0], 0.f));
                o.y = f2h(fmaxf(acc[m][n][1], 0.f));
                o.z = f2h(fmaxf(acc[m][n][2], 0.f));
                o.w = f2h(fmaxf(acc[m][n][3], 0.f));
                *(ushort4*)&hTp[(((size_t)(b * 2 + hh)) << 17) + ((size_t)d << 10) + nn] = o;
            }
    }

    __syncthreads();
    float* tile = (float*)smem;
#pragma unroll
    for (int m = 0; m < MF; m++)
#pragma unroll
        for (int n = 0; n < NF; n++) {
            const int col = wave * NW + n * 16 + lrow;
#pragma unroll
            for (int q = 0; q < 4; q++)
                tile[(m * 16 + lg * 4 + q) * (N + 8) + col] = acc[m][n][q];
        }
    __syncthreads();
#pragma unroll
    for (int p = 0; p < TM * N / 1024; p++) {
        const int idx = t + p * 256;
        const int row = idx / (N / 4), cg = idx % (N / 4);
        float4 v = *(const float4*)&tile[row * (N + 8) + cg * 4];
        if (RELU) {
            v.x = fmaxf(v.x, 0.f); v.y = fmaxf(v.y, 0.f);
            v.z = fmaxf(v.z, 0.f); v.w = fmaxf(v.w, 0.f);
        }
        const int m = row0 + row;
        if (OUT_MODE == 0) {
            *(float4*)&Yf[(size_t)m * N + cg * 4] = v;
        } else {
            ushort4 hi, lo;
            hi.x = f2bf(v.x); lo.x = f2bf(v.x - bf2f(hi.x));
            hi.y = f2bf(v.y); lo.y = f2bf(v.y - bf2f(hi.y));
            hi.z = f2bf(v.z); lo.z = f2bf(v.z - bf2f(hi.z));
            hi.w = f2bf(v.w); lo.w = f2bf(v.w - bf2f(hi.w));
            if (OUT_MODE == 1 || OUT_MODE == 4) {
                const int b = m >> 10, n = m & 1023;
                const int col = cg * 4;
                const int hh = col >> 7, d = col & 127;
                const size_t addr = (((size_t)(b * 2 + hh) << 10) + n) * DD + d;
                if (OUT_MODE == 1) *(float4*)&Yf[addr] = v;
                *(ushort4*)&O1[addr] = hi;
                *(ushort4*)&O2[addr] = lo;
            } else {
                const size_t addr = (size_t)m * N + cg * 4;
                if (OUT_MODE == 3) *(float4*)&Yf[addr] = v;
                *(ushort4*)&O1[addr] = hi;
                *(ushort4*)&O2[addr] = lo;
            }
        }
    }
}

// ---------------------------------------------------------------------------
// e = sym MFMA + FUSED softmax pass A for BOTH branches (partial online
// max/sum per 16-row chunk, read from the LDS tiles; replaces k_smA).
// pm/ps layout [br][bh][jc][k]; tile bijection covers each (jc,k) once.
// ---------------------------------------------------------------------------
__global__ __launch_bounds__(256) void k_esym_mfma(const ushortT* __restrict__ wHi,
                                                   const ushortT* __restrict__ wLo,
                                                   const ushortT* __restrict__ hHi,
                                                   const ushortT* __restrict__ hLo,
                                                   ushortT* __restrict__ e,
                                                   const u64* __restrict__ bits1,
                                                   const u64* __restrict__ bits2,
                                                   float* __restrict__ pm,
                                                   float* __restrict__ ps) {
    __shared__ ushortT smem[20480];
    ushortT* sWjHi = smem;
    ushortT* sWjLo = smem + 2560;
    ushortT* sHjHi = smem + 5120;
    ushortT* sHjLo = smem + 7680;
    ushortT* sWkHi = smem + 10240;
    ushortT* sWkLo = smem + 12800;
    ushortT* sHkHi = smem + 15360;
    ushortT* sHkLo = smem + 17920;

    const int wgid = blockIdx.x;
    const int flat = (wgid & 7) * 272 + (wgid >> 3);
    const int bh = flat / 136;
    int idx = flat % 136, tj = 0;
    while (idx >= 16 - tj) { idx -= 16 - tj; tj++; }
    const int tk = tj + idx;
    const int j0 = tj * 64, k0 = tk * 64;
    const int t = threadIdx.x;
    const int wave = t >> 6, lane = t & 63;
    const int wr = wave >> 1, wc = wave & 1;
    const int lrow = lane & 15, lg = lane >> 4;

    f32x4 acc[2][2];
#pragma unroll
    for (int m = 0; m < 2; m++)
#pragma unroll
        for (int n = 0; n < 2; n++) {
            acc[m][n][0] = 0.f; acc[m][n][1] = 0.f;
            acc[m][n][2] = 0.f; acc[m][n][3] = 0.f;
        }

    const size_t bhbase = (size_t)bh * NN * DD;

    for (int d0 = 0; d0 < DD; d0 += 32) {
        __syncthreads();
        {
            const int row = t >> 2, cu = (t & 3) * 8;
#define STAGE1(SRC, DST, BASE)                                                    \
            *(uint4*)&DST[row * 40 + cu] =                                        \
                *(const uint4*)&SRC[bhbase + (size_t)(BASE + row) * DD + d0 + cu];
            STAGE1(wHi, sWjHi, j0) STAGE1(wLo, sWjLo, j0)
            STAGE1(hHi, sHjHi, j0) STAGE1(hLo, sHjLo, j0)
            STAGE1(wHi, sWkHi, k0) STAGE1(wLo, sWkLo, k0)
            STAGE1(hHi, sHkHi, k0) STAGE1(hLo, sHkLo, k0)
#undef STAGE1
        }
        __syncthreads();

        bf16x8 a0[2], a1[2], b0[2], b1[2];
#pragma unroll
        for (int m = 0; m < 2; m++) {
            const int off = (wr * 32 + m * 16 + lrow) * 40 + lg * 8;
            a0[m] = *(const bf16x8*)&sWjHi[off];
            a1[m] = *(const bf16x8*)&sWjLo[off];
        }
#pragma unroll
        for (int n = 0; n < 2; n++) {
            const int off = (wc * 32 + n * 16 + lrow) * 40 + lg * 8;
            b0[n] = *(const bf16x8*)&sHkHi[off];
            b1[n] = *(const bf16x8*)&sHkLo[off];
        }
#pragma unroll
        for (int m = 0; m < 2; m++)
#pragma unroll
            for (int n = 0; n < 2; n++) {
                acc[m][n] = __builtin_amdgcn_mfma_f32_16x16x32_bf16(a0[m], b0[n], acc[m][n], 0, 0, 0);
                acc[m][n] = __builtin_amdgcn_mfma_f32_16x16x32_bf16(a0[m], b1[n], acc[m][n], 0, 0, 0);
                acc[m][n] = __builtin_amdgcn_mfma_f32_16x16x32_bf16(a1[m], b0[n], acc[m][n], 0, 0, 0);
            }
#pragma unroll
        for (int m = 0; m < 2; m++) {
            const int off = (wr * 32 + m * 16 + lrow) * 40 + lg * 8;
            a0[m] = *(const bf16x8*)&sHjHi[off];
            a1[m] = *(const bf16x8*)&sHjLo[off];
        }
#pragma unroll
        for (int n = 0; n < 2; n++) {
            const int off = (wc * 32 + n * 16 + lrow) * 40 + lg * 8;
            b0[n] = *(const bf16x8*)&sWkHi[off];
            b1[n] = *(const bf16x8*)&sWkLo[off];
        }
#pragma unroll
        for (int m = 0; m < 2; m++)
#pragma unroll
            for (int n = 0; n < 2; n++) {
                acc[m][n] = __builtin_amdgcn_mfma_f32_16x16x32_bf16(a0[m], b0[n], acc[m][n], 0, 0, 0);
                acc[m][n] = __builtin_amdgcn_mfma_f32_16x16x32_bf16(a0[m], b1[n], acc[m][n], 0, 0, 0);
                acc[m][n] = __builtin_amdgcn_mfma_f32_16x16x32_bf16(a1[m], b0[n], acc[m][n], 0, 0, 0);
            }
    }

    __syncthreads();
    ushortT* tileN = smem;
    ushortT* tileT = smem + 4608;
#pragma unroll
    for (int m = 0; m < 2; m++)
#pragma unroll
        for (int n = 0; n < 2; n++) {
            const int jlb = wr * 32 + m * 16 + lg * 4;
            const int kl  = wc * 32 + n * 16 + lrow;
            ushort4 tv;
            tv.x = f2h(acc[m][n][0]); tv.y = f2h(acc[m][n][1]);
            tv.z = f2h(acc[m][n][2]); tv.w = f2h(acc[m][n][3]);
            tileN[(jlb + 0) * 72 + kl] = tv.x;
            tileN[(jlb + 1) * 72 + kl] = tv.y;
            tileN[(jlb + 2) * 72 + kl] = tv.z;
            tileN[(jlb + 3) * 72 + kl] = tv.w;
            *(ushort4*)&tileT[kl * 72 + jlb] = tv;
        }
    __syncthreads();
#pragma unroll
    for (int it = 0; it < 4; it++) {
        const int i2 = t + it * 256;
        const int row = i2 >> 4, ch = (i2 & 15) * 4;
        *(uint2*)&e[((size_t)bh * NN + j0 + row) * NN + k0 + ch] =
            *(const uint2*)&tileN[row * 72 + ch];
        if (tj != tk)
            *(uint2*)&e[((size_t)bh * NN + k0 + row) * NN + j0 + ch] =
                *(const uint2*)&tileT[row * 72 + ch];
    }

    // ---- fused softmax pass A: masked partial max/sum for BOTH branches ----
    {
        const int b_ = bh >> 1;
        const int sub = t >> 6, kcol = t & 63;
        // orientation N: rows j-chunk tj*4+sub, cols k0+kcol, bits word tj
        {
            const int kg = k0 + kcol;
            const u64 w1 = bits1[((size_t)((b_ << 10) | kg)) * 16 + tj];
            const u64 w2 = bits2[((size_t)((b_ << 10) | kg)) * 16 + tj];
            float m1 = 0.f, s1 = 0.f, m2 = 0.f, s2 = 0.f;
#pragma unroll
            for (int rr = 0; rr < 16; rr++) {
                const float ev = h2f(tileN[(sub * 16 + rr) * 72 + kcol]);
                const int bit = sub * 16 + rr;
                if ((w1 >> bit) & 1) {
                    const float mn = fmaxf(m1, ev);
                    s1 = s1 * __expf(m1 - mn) + __expf(ev - mn);
                    m1 = mn;
                }
                if ((w2 >> bit) & 1) {
                    const float mn = fmaxf(m2, ev);
                    s2 = s2 * __expf(m2 - mn) + __expf(ev - mn);
                    m2 = mn;
                }
            }
            const size_t o = (((size_t)bh * 64 + tj * 4 + sub) << 10) + kg;
            pm[o] = m1; ps[o] = s1;
            pm[o + PM_S] = m2; ps[o + PM_S] = s2;
        }
        // mirror: rows k-chunk tk*4+sub, cols j0+kcol, bits word tk
        if (tj != tk) {
            const int jg = j0 + kcol;
            const u64 w1 = bits1[((size_t)((b_ << 10) | jg)) * 16 + tk];
            const u64 w2 = bits2[((size_t)((b_ << 10) | jg)) * 16 + tk];
            float m1 = 0.f, s1 = 0.f, m2 = 0.f, s2 = 0.f;
#pragma unroll
            for (int rr = 0; rr < 16; rr++) {
                const float ev = h2f(tileT[(sub * 16 + rr) * 72 + kcol]);
                const int bit = sub * 16 + rr;
                if ((w1 >> bit) & 1) {
                    const float mn = fmaxf(m1, ev);
                    s1 = s1 * __expf(m1 - mn) + __expf(ev - mn);
                    m1 = mn;
                }
                if ((w2 >> bit) & 1) {
                    const float mn = fmaxf(m2, ev);
                    s2 = s2 * __expf(m2 - mn) + __expf(ev - mn);
                    m2 = mn;
                }
            }
            const size_t o = (((size_t)bh * 64 + tk * 4 + sub) << 10) + jg;
            pm[o] = m1; ps[o] = s1;
            pm[o + PM_S] = m2; ps[o + PM_S] = s2;
        }
    }
}

// ---------------------------------------------------------------------------
__global__ __launch_bounds__(256) void k_buildT(const float* __restrict__ adj,
                                                u64* __restrict__ bits) {
    const int gid = blockIdx.x * 256 + threadIdx.x;
    const int k  = gid & 1023;
    const int tw = (gid >> 10) & 15;
    const int b  = gid >> 14;
    const float* ac = adj + ((size_t)b << 20) + k;
    u64 w = 0;
#pragma unroll 8
    for (int jj = 0; jj < 64; jj++) {
        if (ac[(size_t)(tw * 64 + jj) << 10] != 0.f) w |= 1ull << jj;
    }
    bits[((size_t)((b << 10) | k)) * 16 + tw] = w;
}

__global__ __launch_bounds__(256) void k_cnt(const u64* __restrict__ bits,
                                             int* __restrict__ ccnt) {
    const int gid = blockIdx.x * 256 + threadIdx.x;
    const u64* wb = bits + (size_t)gid * 16;
    int c = 0;
#pragma unroll
    for (int tw = 0; tw < 16; tw++) c += __popcll(wb[tw]);
    ccnt[gid] = c;
}

// ---------------------------------------------------------------------------
// Softmax pass B: gridDim.y = branch.
// ---------------------------------------------------------------------------
__global__ __launch_bounds__(256) void k_smB(const float* __restrict__ pm,
                                             const float* __restrict__ ps,
                                             const int* __restrict__ ccnt,
                                             float* __restrict__ smax,
                                             float* __restrict__ sdinv) {
    const int br = blockIdx.y;
    pm += (size_t)br * PM_S; ps += (size_t)br * PM_S;
    ccnt += (size_t)br * CCNT_S;
    smax += (size_t)br * SM_S; sdinv += (size_t)br * SM_S;
    __shared__ float lm[4][64], ls[4][64];
    const int t = threadIdx.x, q = t >> 6, lane = t & 63;
    const int colg = blockIdx.x * 64 + lane;
    const int bh = colg >> 10, k = colg & 1023;
    const int b  = bh >> 1;
    float M = 0.f, S = 0.f;
#pragma unroll 4
    for (int i = 0; i < 16; i++) {
        const int jc = q * 16 + i;
        const size_t o = (((size_t)bh * 64 + jc) << 10) + k;
        const float pmv = pm[o], psv = ps[o];
        const float mn = fmaxf(M, pmv);
        S = S * __expf(M - mn) + psv * __expf(pmv - mn);
        M = mn;
    }
    lm[q][lane] = M; ls[q][lane] = S;
    __syncthreads();
    if (q == 0) {
#pragma unroll
        for (int qq = 1; qq < 4; qq++) {
            const float pmv = lm[qq][lane], psv = ls[qq][lane];
            const float mn = fmaxf(M, pmv);
            S = S * __expf(M - mn) + psv * __expf(pmv - mn);
            M = mn;
        }
        S += (float)(NN - ccnt[(b << 10) + k]) * __expf(-M);
        smax[colg] = M;
        sdinv[colg] = 1.f / S;
    }
}

// Softmax pass C: gridDim.y = branch.
__global__ __launch_bounds__(256) void k_smC(const ushortT* __restrict__ e,
                                             const u64* __restrict__ bits,
                                             const float* __restrict__ smax,
                                             const float* __restrict__ sdinv,
                                             ushortT* __restrict__ att) {
    const int br = blockIdx.y;
    bits += (size_t)br * BITS_S;
    smax += (size_t)br * SM_S; sdinv += (size_t)br * SM_S;
    att  += (size_t)br * ATT_S;
    const int gid = blockIdx.x * 256 + threadIdx.x;
    const int kg = gid & 255;
    const int jc = (gid >> 8) & 63;
    const int bh = gid >> 14;
    const int b  = bh >> 1;
    const int k4 = kg * 4;
    const int tw = jc >> 2;
    const int bo = (jc & 3) * 16;
    u64 w[4];
#pragma unroll
    for (int i = 0; i < 4; i++)
        w[i] = bits[((size_t)((b << 10) | (k4 + i))) * 16 + tw];
    const float4 m4 = *(const float4*)&smax[(bh << 10) + k4];
    const float4 d4 = *(const float4*)&sdinv[(bh << 10) + k4];
    const float ms[4] = {m4.x, m4.y, m4.z, m4.w};
    const float ds[4] = {d4.x, d4.y, d4.z, d4.w};
    const ushortT* ec = e + ((size_t)bh << 20) + (size_t)(jc * 16) * NN + k4;
    ushortT* ac = att + ((size_t)bh << 20) + (size_t)(jc * 16) * NN + k4;
#pragma unroll
    for (int r = 0; r < 16; r++) {
        const ushort4 ev = *(const ushort4*)&ec[(size_t)r * NN];
        const float evs[4] = {h2f(ev.x), h2f(ev.y), h2f(ev.z), h2f(ev.w)};
        ushort4 o;
        ushortT os[4];
#pragma unroll
        for (int i = 0; i < 4; i++) {
            const bool on = (w[i] >> (bo + r)) & 1;
            os[i] = f2h(on ? __expf(evs[i] - ms[i]) * ds[i] : 0.f);
        }
        o.x = os[0]; o.y = os[1]; o.z = os[2]; o.w = os[3];
        *(ushort4*)&ac[(size_t)r * NN] = o;
    }
}

// ---------------------------------------------------------------------------
// Dense f16 MFMA hop, 8 waves, j-chunk 128, XCD swizzle. gridDim.y = branch.
// MODE 0: zin = hT; beta computed in-block, writes mixed z1.
// MODE 1: zin = previous mixed z; beta from global.
// SPLIT:  write relu+bf16-split z [bh][n][d] (fused fin); no zT output.
// ---------------------------------------------------------------------------
template<int MODE, bool SPLIT>
__global__ __launch_bounds__(512) void k_hop(const ushortT* __restrict__ att,
                                             const ushortT* __restrict__ zin,
                                             const ushortT* __restrict__ hT,
                                             float* __restrict__ beta,
                                             const float* __restrict__ Wbw,
                                             const float* __restrict__ Wbb,
                                             ushortT* __restrict__ zout,
                                             ushortT* __restrict__ zHi,
                                             ushortT* __restrict__ zLo) {
    __shared__ ushortT smem[64 * 136 + 128 * 136];
    ushortT* sA = smem;
    ushortT* sB = smem + 64 * 136;
    const int br = blockIdx.y;
    att += (size_t)br * ATT_S;
    beta += (size_t)br * SM_S;
    if (zin)  zin  += (size_t)br * Z_S;
    if (zout) zout += (size_t)br * Z_S;
    if (SPLIT) { zHi += (size_t)br * Z_S; zLo += (size_t)br * Z_S; }
    const int bid = blockIdx.x;                 // 256 = 8 XCD x 32
    const int flat = (bid & 7) * 32 + (bid >> 3);
    const int bh = flat >> 4;
    const int i0 = (flat & 15) * 64;
    const int t = threadIdx.x, wave = t >> 6, lane = t & 63;
    const int wr = wave >> 2, wc = wave & 3;
    const int lrow = lane & 15, lg = lane >> 4;
    const ushortT* attb = att + ((size_t)bh << 20);
    const ushortT* hTb  = hT + (size_t)bh * 131072;
    const ushortT* zb   = (MODE == 0) ? hTb : zin + (size_t)bh * 131072;

    f32x4 acc[2][2];
#pragma unroll
    for (int m = 0; m < 2; m++)
#pragma unroll
        for (int n = 0; n < 2; n++) {
            acc[m][n][0]=0.f; acc[m][n][1]=0.f; acc[m][n][2]=0.f; acc[m][n][3]=0.f;
        }

    for (int j0 = 0; j0 < NN; j0 += 128) {
        __syncthreads();
#pragma unroll
        for (int q = 0; q < 2; q++) {
            const int u = t + q * 512;
            const int row = u >> 4, c8 = (u & 15) * 8;
            *(uint4*)&sA[row * 136 + c8] =
                *(const uint4*)&attb[(size_t)(i0 + row) * NN + j0 + c8];
        }
#pragma unroll
        for (int q = 0; q < 4; q++) {
            const int u = t + q * 512;
            const int row = u >> 4, c8 = (u & 15) * 8;
            *(uint4*)&sB[row * 136 + c8] =
                *(const uint4*)&zb[(size_t)row * NN + j0 + c8];
        }
        __syncthreads();
#pragma unroll
        for (int ks = 0; ks < 4; ks++) {
            f16x8 a[2], b[2];
#pragma unroll
            for (int m = 0; m < 2; m++)
                a[m] = *(const f16x8*)&sA[(wr * 32 + m * 16 + lrow) * 136 + ks * 32 + lg * 8];
#pragma unroll
            for (int n = 0; n < 2; n++)
                b[n] = *(const f16x8*)&sB[(wc * 32 + n * 16 + lrow) * 136 + ks * 32 + lg * 8];
#pragma unroll
            for (int m = 0; m < 2; m++)
#pragma unroll
                for (int n = 0; n < 2; n++)
                    acc[m][n] = __builtin_amdgcn_mfma_f32_16x16x32_f16(a[m], b[n], acc[m][n], 0, 0, 0);
        }
    }

    ushortT* zo = SPLIT ? nullptr : zout + (size_t)bh * 131072;
    ushortT* ztile = nullptr;

    if (MODE == 1) {
        const float* betab = beta + ((size_t)bh << 10);
        if (SPLIT) { __syncthreads(); ztile = smem; }
#pragma unroll
        for (int m = 0; m < 2; m++)
#pragma unroll
            for (int n = 0; n < 2; n++) {
                const int d = wc * 32 + n * 16 + lrow;
                const int i = i0 + wr * 32 + m * 16 + lg * 4;
                const float4 bev = *(const float4*)&betab[i];
                const ushort4 hv = *(const ushort4*)&hTb[(size_t)d * NN + i];
                ushort4 o;
                o.x = f2h(bev.x * h2f(hv.x) + (1.f - bev.x) * fmaxf(acc[m][n][0], 0.f));
                o.y = f2h(bev.y * h2f(hv.y) + (1.f - bev.y) * fmaxf(acc[m][n][1], 0.f));
                o.z = f2h(bev.z * h2f(hv.z) + (1.f - bev.z) * fmaxf(acc[m][n][2], 0.f));
                o.w = f2h(bev.w * h2f(hv.w) + (1.f - bev.w) * fmaxf(acc[m][n][3], 0.f));
                if (SPLIT) {
                    const int il = wr * 32 + m * 16 + lg * 4;
                    ztile[(il + 0) * 136 + d] = o.x;
                    ztile[(il + 1) * 136 + d] = o.y;
                    ztile[(il + 2) * 136 + d] = o.z;
                    ztile[(il + 3) * 136 + d] = o.w;
                } else {
                    *(ushort4*)&zo[(size_t)d * NN + i] = o;
                }
            }
    } else {
        ushort4 ofrag[2][2];
#pragma unroll
        for (int m = 0; m < 2; m++)
#pragma unroll
            for (int n = 0; n < 2; n++) {
                ushort4 o;
                o.x = f2h(fmaxf(acc[m][n][0], 0.f));
                o.y = f2h(fmaxf(acc[m][n][1], 0.f));
                o.z = f2h(fmaxf(acc[m][n][2], 0.f));
                o.w = f2h(fmaxf(acc[m][n][3], 0.f));
                ofrag[m][n] = o;
            }
        __syncthreads();
        ushortT* azl = smem;                    // [128][72]
        ushortT* hl  = smem + 128 * 72;         // [128][72]
        float*   bl  = (float*)(smem + 2 * 128 * 72);  // [64]
#pragma unroll
        for (int m = 0; m < 2; m++)
#pragma unroll
            for (int n = 0; n < 2; n++) {
                const int d = wc * 32 + n * 16 + lrow;
                const int il = wr * 32 + m * 16 + lg * 4;
                const ushort4 o = ofrag[m][n];
                azl[d * 72 + il + 0] = o.x;
                azl[d * 72 + il + 1] = o.y;
                azl[d * 72 + il + 2] = o.z;
                azl[d * 72 + il + 3] = o.w;
            }
#pragma unroll
        for (int q = 0; q < 2; q++) {
            const int u = t + q * 512;
            const int row = u >> 3, c8 = (u & 7) * 8;
            *(uint4*)&hl[row * 72 + c8] =
                *(const uint4*)&hTb[(size_t)row * NN + i0 + c8];
        }
        __syncthreads();
        {
            const int i = t >> 3, c = t & 7;
            float p = 0.f;
#pragma unroll
            for (int dd = 0; dd < 16; dd++) {
                const int d = c * 16 + dd;
                p += h2f(hl[d * 72 + i]) * Wbw[d] + h2f(azl[d * 72 + i]) * Wbw[DD + d];
            }
            p += __shfl_down(p, 4, 8);
            p += __shfl_down(p, 2, 8);
            p += __shfl_down(p, 1, 8);
            if (c == 0) {
                const float be = 1.f / (1.f + expf(-(p + Wbb[0])));
                beta[(bh << 10) + i0 + i] = be;
                bl[i] = be;
            }
        }
        __syncthreads();
        if (SPLIT) ztile = smem;                // reuse azl region
#pragma unroll
        for (int m = 0; m < 2; m++)
#pragma unroll
            for (int n = 0; n < 2; n++) {
                const int d = wc * 32 + n * 16 + lrow;
                const int il = wr * 32 + m * 16 + lg * 4;
                const ushort4 az = ofrag[m][n];
                ushort4 o;
                o.x = f2h(bl[il+0] * h2f(hl[d*72+il+0]) + (1.f - bl[il+0]) * h2f(az.x));
                o.y = f2h(bl[il+1] * h2f(hl[d*72+il+1]) + (1.f - bl[il+1]) * h2f(az.y));
                o.z = f2h(bl[il+2] * h2f(hl[d*72+il+2]) + (1.f - bl[il+2]) * h2f(az.z));
                o.w = f2h(bl[il+3] * h2f(hl[d*72+il+3]) + (1.f - bl[il+3]) * h2f(az.w));
                if (SPLIT) {
                    ztile[(il + 0) * 136 + d] = o.x;
                    ztile[(il + 1) * 136 + d] = o.y;
                    ztile[(il + 2) * 136 + d] = o.z;
                    ztile[(il + 3) * 136 + d] = o.w;
                } else {
                    *(ushort4*)&zo[(size_t)d * NN + i0 + il] = o;
                }
            }
    }

    if (SPLIT) {
        __syncthreads();
        const size_t obase = (size_t)bh * 131072 + (size_t)i0 * DD;
#pragma unroll
        for (int p = 0; p < 2; p++) {
            const int idx = t + p * 512;
            const int row = idx >> 4, dq = (idx & 15) * 8;
            ushortT zv[8], hi8[8], lo8[8];
            *(uint4*)zv = *(const uint4*)&ztile[row * 136 + dq];
#pragma unroll
            for (int i = 0; i < 8; i++) {
                const float v = fmaxf(h2f(zv[i]), 0.f);
                hi8[i] = f2bf(v);
                lo8[i] = f2bf(v - bf2f(hi8[i]));
            }
            *(uint4*)&zHi[obase + (size_t)row * DD + dq] = *(uint4*)hi8;
            *(uint4*)&zLo[obase + (size_t)row * DD + dq] = *(uint4*)lo8;
        }
    }
}

// c = c2 - c1 fp32 + bf16 hi/lo split
__global__ __launch_bounds__(256) void k_sub(const float* __restrict__ c2,
                                             const float* __restrict__ c1,
                                             float* __restrict__ c,
                                             ushortT* __restrict__ cHi,
                                             ushortT* __restrict__ cLo) {
    const int g = blockIdx.x * 256 + threadIdx.x;
    const float4 a = ((const float4*)c2)[g];
    const float4 b = ((const float4*)c1)[g];
    const float4 v = make_float4(a.x - b.x, a.y - b.y, a.z - b.z, a.w - b.w);
    ((float4*)c)[g] = v;
    ushort4 hi, lo;
    hi.x = f2bf(v.x); lo.x = f2bf(v.x - bf2f(hi.x));
    hi.y = f2bf(v.y); lo.y = f2bf(v.y - bf2f(hi.y));
    hi.z = f2bf(v.z); lo.z = f2bf(v.z - bf2f(hi.z));
    hi.w = f2bf(v.w); lo.w = f2bf(v.w - bf2f(hi.w));
    ((ushort4*)cHi)[g] = hi;
    ((ushort4*)cLo)[g] = lo;
}

__global__ __launch_bounds__(128) void k_poolA(const float* __restrict__ c,
                                               const float* __restrict__ valid,
                                               float* __restrict__ pp,
                                               float* __restrict__ pv) {
    const int bc = blockIdx.x;
    const int b = bc >> 4, ch = bc & 15;
    const int d = threadIdx.x;
    const float* cb = c + ((size_t)b << 17) + (size_t)(ch * 64) * DD;
    const float* vb = valid + (b << 10) + ch * 64;
    float s = 0.f, sv = 0.f;
#pragma unroll 8
    for (int i = 0; i < 64; i++) { const float v = vb[i]; s += cb[(size_t)i * DD + d] * v; sv += v; }
    pp[bc * 128 + d] = s;
    if (d == 0) pv[bc] = sv;
}

__global__ __launch_bounds__(256) void k_poolB(const float* __restrict__ pp,
                                               const float* __restrict__ pv,
                                               float* __restrict__ pooled) {
    const int gid = blockIdx.x * 256 + threadIdx.x;
    const int b = gid >> 7, d = gid & 127;
    float s = 0.f, sv = 0.f;
#pragma unroll
    for (int ch = 0; ch < 16; ch++) {
        s  += pp[(b * 16 + ch) * 128 + d];
        sv += pv[b * 16 + ch];
    }
    pooled[b * 128 + d] = s / sv;
}

template<int K, int NOUT, bool RELU>
__global__ void k_fc(const float* __restrict__ X, const float* __restrict__ W,
                     const float* __restrict__ bias, float* __restrict__ Y) {
    const int gid = blockIdx.x * blockDim.x + threadIdx.x;
    if (gid >= BB * NOUT) return;
    const int b = gid / NOUT, o = gid % NOUT;
    float s = bias[o];
    for (int i = 0; i < K; i++) s += X[(size_t)b * K + i] * W[(size_t)i * NOUT + o];
    Y[gid] = RELU ? fmaxf(s, 0.f) : s;
}

__global__ void k_fc2(const float* __restrict__ X, const float* __restrict__ W,
                      const float* __restrict__ bias, float* __restrict__ out) {
    const int b = threadIdx.x >> 6, lane = threadIdx.x & 63;
    float s = 0.f;
    for (int i = lane; i < DFCN; i += 64) s += X[(size_t)b * DFCN + i] * W[i];
#pragma unroll
    for (int off = 32; off > 0; off >>= 1) s += __shfl_down(s, off);
    if (lane == 0) out[b] = 1.f / (1.f + expf(-(s + bias[0])));
}

// ---------------------------------------------------------------------------
extern "C" void kernel_launch(void* const* d_in, const int* in_sizes, int n_in,
                              void* d_out, int out_size, void* d_ws, size_t ws_size,
                              hipStream_t stream) {
    const float* x        = (const float*)d_in[0];
    const float* adj1     = (const float*)d_in[1];
    const float* adj2     = (const float*)d_in[2];
    const float* valid    = (const float*)d_in[3];
    const float* embede_w = (const float*)d_in[4];
    const float* Wh       = (const float*)d_in[5];
    const float* We       = (const float*)d_in[6];
    const float* Wbw      = (const float*)d_in[7];
    const float* Wbb      = (const float*)d_in[8];
    const float* Wo       = (const float*)d_in[9];
    const float* fc0_w    = (const float*)d_in[10];
    const float* fc0_b    = (const float*)d_in[11];
    const float* fc1_w    = (const float*)d_in[12];
    const float* fc1_b    = (const float*)d_in[13];
    const float* fc2_w    = (const float*)d_in[14];
    const float* fc2_b    = (const float*)d_in[15];

    // ---- workspace carve (~190 MB; ws poison shows ~268 MB available) ----
    float* ws = (float*)d_ws;
    float* c      = ws;                          // 1,048,576 f
    float* c1     = c      + (size_t)1048576;    // [2] branches: c1, c2 contiguous
    float* c2     = c1     + (size_t)C_S;
    float* beta   = c2     + (size_t)1048576;    // [2] x 16,384 f
    float* pm     = beta   + (size_t)2 * SM_S;   // [2] x 1,048,576 f
    float* ps     = pm     + (size_t)2 * PM_S;   // [2] x 1,048,576 f
    float* smax   = ps     + (size_t)2 * PM_S;   // [2] x 16,384 f
    float* sdinv  = smax   + (size_t)2 * SM_S;   // [2] x 16,384 f
    float* pp     = sdinv  + (size_t)2 * SM_S;   // 16,384 f
    float* pv     = pp     + (size_t)16384;      // 128 f
    float* pooled = pv     + (size_t)128;        // 1,024 f
    float* f0     = pooled + (size_t)1024;       // 4,096 f
    float* f1     = f0     + (size_t)4096;       // 4,096 f
    ushortT* hHi  = (ushortT*)(f1 + 4096);       // 2,097,152 us each
    ushortT* hLo  = hHi + (size_t)2097152;
    ushortT* wHi  = hLo + (size_t)2097152;
    ushortT* wLo  = wHi + (size_t)2097152;
    ushortT* hT   = wLo + (size_t)2097152;
    ushortT* zTa  = hT  + (size_t)2097152;       // [2] x 2,097,152
    ushortT* zTb  = zTa + (size_t)2 * Z_S;       // [2] x 2,097,152
    ushortT* cHi  = zTb + (size_t)2 * Z_S;       // 1,048,576 us each
    ushortT* cLo  = cHi + (size_t)1048576;
    ushortT* zHi  = cLo + (size_t)1048576;       // [2] x 2,097,152
    ushortT* zLo  = zHi + (size_t)2 * Z_S;       // [2] x 2,097,152
    ushortT* att  = zLo + (size_t)2 * Z_S;       // [2] x 16,777,216
    ushortT* e    = att + (size_t)2 * ATT_S;     // 16,777,216 us
    ushortT* WhTh = e   + (size_t)16777216;      // 131,072 us each
    ushortT* WhTl = WhTh + (size_t)131072;
    ushortT* WeTh = WhTl + (size_t)131072;       // 65,536 each
    ushortT* WeTl = WeTh + (size_t)65536;
    ushortT* WoTh = WeTl + (size_t)65536;        // 131,072 each
    ushortT* WoTl = WoTh + (size_t)131072;
    ushortT* EmTh = WoTl + (size_t)131072;       // 16,384 each
    ushortT* EmTl = EmTh + (size_t)16384;
    u64* bits1    = (u64*)(EmTl + (size_t)16384); // [2] x 131,072 u64 contiguous
    u64* bits2    = bits1 + (size_t)BITS_S;
    int* ccnt1    = (int*)(bits2 + (size_t)BITS_S); // [2] x 8,192 contiguous
    int* ccnt2    = ccnt1 + CCNT_S;

    // ---- one-time per launch: masks + weight splits ----
    k_buildT<<<512, 256, 0, stream>>>(adj1, bits1);
    k_buildT<<<512, 256, 0, stream>>>(adj2, bits2);
    k_cnt<<<32, 256, 0, stream>>>(bits1, ccnt1);
    k_cnt<<<32, 256, 0, stream>>>(bits2, ccnt2);
    k_splitWT<128,256><<<dim3(8,4,4), 256, 0, stream>>>(Wh, WhTh, WhTl);
    k_splitWT<128,128><<<dim3(4,4,4), 256, 0, stream>>>(We, WeTh, WeTl);
    k_splitWT<256,128><<<dim3(4,8,4), 256, 0, stream>>>(Wo, WoTh, WoTl);
    k_splitWT<128,128><<<dim3(4,4,1), 256, 0, stream>>>(embede_w, EmTh, EmTl);

    // c = x @ embede_w
    k_mgemm<128,128,32,false,2,3><<<256, 256, 0, stream>>>(
        nullptr, nullptr, x, EmTh, EmTl, c, cHi, cLo, 0, 0);

    for (int k = 0; k < LL; k++) {
        const int nhop = k + 1;
        const float* Wbw_k = Wbw + (size_t)k * 256;
        const float* Wbb_k = Wbb + k;
        // h = relu(c @ Wh[k]) -> splits [bh][n][d] + hT f16 [bh][d][n]
        k_mgemm<128,256,32,true,0,4><<<256, 256, 0, stream>>>(
            cHi, cLo, nullptr, WhTh + (size_t)k*32768, WhTl + (size_t)k*32768,
            (float*)hT, hHi, hLo, 0, 0);
        // hW = h @ We[k] -> splits row-major
        k_mgemm<128,128,64,false,0,2><<<256, 256, 0, stream>>>(
            hHi, hLo, nullptr, WeTh + (size_t)k*16384, WeTl + (size_t)k*16384,
            nullptr, wHi, wLo, 0, 0);
        // e + fused softmax partials for both branches
        k_esym_mfma<<<2176, 256, 0, stream>>>(wHi, wLo, hHi, hLo, e,
                                              bits1, bits2, pm, ps);

        // both branches merged via gridDim.y = 2
        k_smB<<<dim3(256,2), 256, 0, stream>>>(pm, ps, ccnt1, smax, sdinv);
        k_smC<<<dim3(1024,2), 256, 0, stream>>>(e, bits1, smax, sdinv, att);

        if (nhop == 1) {
            k_hop<0,true><<<dim3(256,2), 512, 0, stream>>>(
                att, nullptr, hT, beta, Wbw_k, Wbb_k, nullptr, zHi, zLo);
        } else {
            k_hop<0,false><<<dim3(256,2), 512, 0, stream>>>(
                att, nullptr, hT, beta, Wbw_k, Wbb_k, zTb, nullptr, nullptr);
            ushortT* zA = zTb; ushortT* zB = zTa;
            for (int tpp = 1; tpp < nhop; tpp++) {
                if (tpp == nhop - 1) {
                    k_hop<1,true><<<dim3(256,2), 512, 0, stream>>>(
                        att, zA, hT, beta, nullptr, nullptr, nullptr, zHi, zLo);
                } else {
                    k_hop<1,false><<<dim3(256,2), 512, 0, stream>>>(
                        att, zA, hT, beta, nullptr, nullptr, zB, nullptr, nullptr);
                    ushortT* tmp = zA; zA = zB; zB = tmp;
                }
            }
        }
        // cb = relu(z) @ Wo[k], both branches (brA = zHi stride, brY = c stride)
        k_mgemm<256,128,32,false,1,0><<<dim3(256,2), 256, 0, stream>>>(
            zHi, zLo, nullptr, WoTh + (size_t)k*32768, WoTl + (size_t)k*32768,
            c1, nullptr, nullptr, (int)Z_S, (int)C_S);

        k_sub<<<1024, 256, 0, stream>>>(c2, c1, c, cHi, cLo);
    }

    k_poolA<<<128, 128, 0, stream>>>(c, valid, pp, pv);
    k_poolB<<<4, 256, 0, stream>>>(pp, pv, pooled);
    k_fc<128, DFCN, true><<<16, 256, 0, stream>>>(pooled, fc0_w, fc0_b, f0);
    k_fc<DFCN, DFCN, true><<<16, 256, 0, stream>>>(f0, fc1_w, fc1_b, f1);
    k_fc2<<<1, 512, 0, stream>>>(f1, fc2_w, fc2_b, (float*)d_out);
}